// Round 1
// baseline (2238.076 us; speedup 1.0000x reference)
//
#include <hip/hip_runtime.h>

#define D 128

// ---------------- degree / edge weight ----------------
__global__ void k_init_deg(float* __restrict__ deg, int n) {
    int i = blockIdx.x * blockDim.x + threadIdx.x;
    if (i < n) deg[i] = 1.0f;  // self-loop weight
}

__global__ void k_edge_w(const int* __restrict__ ea, const float* __restrict__ bt,
                         const int* __restrict__ col, float* __restrict__ ew,
                         float* __restrict__ deg, int E) {
    int e = blockIdx.x * blockDim.x + threadIdx.x;
    if (e >= E) return;
    float w = bt[ea[3 * e + 0]] + bt[16 + ea[3 * e + 1]] + bt[32 + ea[3 * e + 2]];
    ew[e] = w;
    atomicAdd(&deg[col[e]], w);
}

__global__ void k_dinv(float* __restrict__ deg, int n) {
    int i = blockIdx.x * blockDim.x + threadIdx.x;
    if (i < n) {
        float d = deg[i];
        deg[i] = d > 0.f ? rsqrtf(d) : 0.f;
    }
}

// ---------------- atom encoder ----------------
__global__ void k_atom(const int* __restrict__ x, const float* __restrict__ at,
                       float* __restrict__ h, int n) {
    int node = blockIdx.x * 2 + (threadIdx.x >> 7);
    int d = threadIdx.x & 127;
    if (node >= n) return;
    const int* xr = x + node * 9;
    float s = 0.f;
#pragma unroll
    for (int f = 0; f < 9; ++f)
        s += at[(xr[f] + f * 64) * D + d];
    h[(long)node * D + d] = s;
}

// ---------------- matmul: out[n,:] = (RELU? max(h,0):h) @ W ----------------
// block 256 threads -> 128 rows x 128 cols tile, per-thread 8x8, K chunked by 64.
#define KC 64
template <bool RELU>
__global__ __launch_bounds__(256) void k_matmul(const float* __restrict__ h,
                                                const float* __restrict__ W,
                                                float* __restrict__ out, int n) {
    __shared__ float hsT[KC * 129];  // [k][r] transposed, stride 129 (conflict-free b32)
    __shared__ float Ws[KC * 128];   // [k][c]
    const int tid = threadIdx.x;
    const int tr = tid >> 4;   // 0..15
    const int tc = tid & 15;   // 0..15
    const int r0 = tr * 8, c0 = tc * 8;
    const long row0 = (long)blockIdx.x * 128;
    float acc[8][8] = {};
    for (int kc = 0; kc < D; kc += KC) {
        // stage h chunk transposed
        for (int i = tid; i < 128 * (KC / 4); i += 256) {
            int r = i >> 4;    // 16 float4 per row-chunk
            int k4 = i & 15;
            long row = row0 + r;
            float4 v = make_float4(0.f, 0.f, 0.f, 0.f);
            if (row < n) v = *(const float4*)(h + row * D + kc + k4 * 4);
            if (RELU) {
                v.x = fmaxf(v.x, 0.f); v.y = fmaxf(v.y, 0.f);
                v.z = fmaxf(v.z, 0.f); v.w = fmaxf(v.w, 0.f);
            }
            int kb = k4 * 4;
            hsT[(kb + 0) * 129 + r] = v.x;
            hsT[(kb + 1) * 129 + r] = v.y;
            hsT[(kb + 2) * 129 + r] = v.z;
            hsT[(kb + 3) * 129 + r] = v.w;
        }
        // stage W chunk (rows kc..kc+KC-1, full width)
        for (int i = tid; i < KC * 32; i += 256)
            ((float4*)Ws)[i] = *(const float4*)(W + (long)kc * D + i * 4);
        __syncthreads();
        for (int k = 0; k < KC; ++k) {
            float hv[8], wv[8];
#pragma unroll
            for (int j = 0; j < 8; ++j) hv[j] = hsT[k * 129 + r0 + j];
            float4 w0 = *(const float4*)(&Ws[k * 128 + c0]);
            float4 w1 = *(const float4*)(&Ws[k * 128 + c0 + 4]);
            wv[0] = w0.x; wv[1] = w0.y; wv[2] = w0.z; wv[3] = w0.w;
            wv[4] = w1.x; wv[5] = w1.y; wv[6] = w1.z; wv[7] = w1.w;
#pragma unroll
            for (int a = 0; a < 8; ++a)
#pragma unroll
                for (int b = 0; b < 8; ++b)
                    acc[a][b] += hv[a] * wv[b];
        }
        __syncthreads();
    }
#pragma unroll
    for (int a = 0; a < 8; ++a) {
        long row = row0 + r0 + a;
        if (row < n) {
            *(float4*)(out + row * D + c0) =
                make_float4(acc[a][0], acc[a][1], acc[a][2], acc[a][3]);
            *(float4*)(out + row * D + c0 + 4) =
                make_float4(acc[a][4], acc[a][5], acc[a][6], acc[a][7]);
        }
    }
}

// ---------------- self-loop + bias init: out = b + hW * dinv^2 ----------------
__global__ void k_self_bias(const float* __restrict__ hW, const float* __restrict__ bias,
                            const float* __restrict__ dinv, float* __restrict__ out, int n) {
    int node = blockIdx.x * 2 + (threadIdx.x >> 7);
    int d = threadIdx.x & 127;
    if (node >= n) return;
    float di = dinv[node];
    long idx = (long)node * D + d;
    out[idx] = bias[d] + hW[idx] * di * di;
}

// ---------------- edge scatter: out[col] += hW[row] * norm ----------------
__global__ void k_scatter(const float* __restrict__ hW, const int* __restrict__ row,
                          const int* __restrict__ col, const float* __restrict__ ew,
                          const float* __restrict__ dinv, float* __restrict__ out, int E) {
    long tid = (long)blockIdx.x * blockDim.x + threadIdx.x;
    int e = (int)(tid >> 5);
    if (e >= E) return;
    int q = (int)(tid & 31) << 2;
    int r = row[e], c = col[e];
    float nrm = dinv[r] * ew[e] * dinv[c];
    float4 h4 = *(const float4*)(hW + (long)r * D + q);
    float* o = out + (long)c * D + q;
    atomicAdd(o + 0, h4.x * nrm);
    atomicAdd(o + 1, h4.y * nrm);
    atomicAdd(o + 2, h4.z * nrm);
    atomicAdd(o + 3, h4.w * nrm);
}

// ---------------- final: sigmoid(h @ lin_W + lin_b) ----------------
__global__ void k_final(const float* __restrict__ h, const float* __restrict__ linW,
                        const float* __restrict__ linb, float* __restrict__ out, int n) {
    long gt = (long)blockIdx.x * blockDim.x + threadIdx.x;
    int node = (int)(gt >> 6);
    int lane = threadIdx.x & 63;
    if (node >= n) return;
    float2 hv = *(const float2*)(h + (long)node * D + lane * 2);
    float2 wv = *(const float2*)(linW + lane * 2);
    float s = hv.x * wv.x + hv.y * wv.y;
#pragma unroll
    for (int off = 32; off; off >>= 1) s += __shfl_down(s, off);
    if (lane == 0) out[node] = 1.f / (1.f + expf(-(s + linb[0])));
}

extern "C" void kernel_launch(void* const* d_in, const int* in_sizes, int n_in,
                              void* d_out, int out_size, void* d_ws, size_t ws_size,
                              hipStream_t stream) {
    const int* x          = (const int*)d_in[0];
    const int* edge_index = (const int*)d_in[1];
    const int* edge_attr  = (const int*)d_in[2];
    const float* atom_table = (const float*)d_in[3];
    const float* bond_table = (const float*)d_in[4];
    const float* W1 = (const float*)d_in[5];
    const float* b1 = (const float*)d_in[6];
    const float* W2 = (const float*)d_in[7];
    const float* b2 = (const float*)d_in[8];
    const float* lin_W = (const float*)d_in[9];
    const float* lin_b = (const float*)d_in[10];
    float* out = (float*)d_out;

    const int N = in_sizes[0] / 9;
    const int E = in_sizes[1] / 2;
    const int* row = edge_index;      // edge_index[0]
    const int* col = edge_index + E;  // edge_index[1]

    float* ws = (float*)d_ws;
    float* ew   = ws;                       // E
    float* dinv = ew + E;                   // N
    float* bufA = dinv + N;                 // N*128  (h0, later hW2)
    float* bufB = bufA + (long)N * D;       // N*128  (hW1, later out2)
    float* bufC = bufB + (long)N * D;       // N*128  (out1)

    // degree + edge weights
    k_init_deg<<<(N + 255) / 256, 256, 0, stream>>>(dinv, N);
    k_edge_w<<<(E + 255) / 256, 256, 0, stream>>>(edge_attr, bond_table, col, ew, dinv, E);
    k_dinv<<<(N + 255) / 256, 256, 0, stream>>>(dinv, N);

    // atom encoder -> bufA
    k_atom<<<(N + 1) / 2, 256, 0, stream>>>(x, atom_table, bufA, N);

    // layer 1: hW = h0 @ W1 -> bufB ; out1 = b1 + self + scatter -> bufC
    int mm_grid = (N + 127) / 128;
    k_matmul<false><<<mm_grid, 256, 0, stream>>>(bufA, W1, bufB, N);
    k_self_bias<<<(N + 1) / 2, 256, 0, stream>>>(bufB, b1, dinv, bufC, N);
    k_scatter<<<(int)(((long)E * 32 + 255) / 256), 256, 0, stream>>>(bufB, row, col, ew, dinv, bufC, E);

    // layer 2: hW2 = relu(out1) @ W2 -> bufA ; out2 = b2 + self + scatter -> bufB
    k_matmul<true><<<mm_grid, 256, 0, stream>>>(bufC, W2, bufA, N);
    k_self_bias<<<(N + 1) / 2, 256, 0, stream>>>(bufA, b2, dinv, bufB, N);
    k_scatter<<<(int)(((long)E * 32 + 255) / 256), 256, 0, stream>>>(bufA, row, col, ew, dinv, bufB, E);

    // final linear + sigmoid
    k_final<<<(N + 3) / 4, 256, 0, stream>>>(bufB, lin_W, lin_b, out, N);
}

// Round 2
// 407.460 us; speedup vs baseline: 5.4928x; 5.4928x over previous
//
#include <hip/hip_runtime.h>

#define D 128

// ---------------- init: deg=1 (self loop), cnt=0 ----------------
__global__ void k_init(float* __restrict__ deg, int* __restrict__ cnt, int n) {
    int i = blockIdx.x * blockDim.x + threadIdx.x;
    if (i < n) { deg[i] = 1.0f; cnt[i] = 0; }
}

// ---------------- edge weight + degree + in-degree count ----------------
__global__ void k_edge_w(const int* __restrict__ ea, const float* __restrict__ bt,
                         const int* __restrict__ col, float* __restrict__ ew,
                         float* __restrict__ deg, int* __restrict__ cnt, int E) {
    int e = blockIdx.x * blockDim.x + threadIdx.x;
    if (e >= E) return;
    float w = bt[ea[3 * e + 0]] + bt[16 + ea[3 * e + 1]] + bt[32 + ea[3 * e + 2]];
    ew[e] = w;
    int c = col[e];
    atomicAdd(&deg[c], w);
    atomicAdd(&cnt[c], 1);
}

__global__ void k_dinv(float* __restrict__ deg, int n) {
    int i = blockIdx.x * blockDim.x + threadIdx.x;
    if (i < n) {
        float d = deg[i];
        deg[i] = d > 0.f ? rsqrtf(d) : 0.f;
    }
}

// ---------------- exclusive scan (3-phase) ----------------
#define SCAN_B 256
__global__ void k_scan1(const int* __restrict__ cnt, int* __restrict__ off,
                        int* __restrict__ bsums, int n) {
    __shared__ int s[SCAN_B];
    int tid = threadIdx.x;
    int i = blockIdx.x * SCAN_B + tid;
    int v = (i < n) ? cnt[i] : 0;
    s[tid] = v;
    __syncthreads();
    for (int o = 1; o < SCAN_B; o <<= 1) {
        int t = (tid >= o) ? s[tid - o] : 0;
        __syncthreads();
        s[tid] += t;
        __syncthreads();
    }
    if (i < n) off[i] = s[tid] - v;           // exclusive
    if (tid == SCAN_B - 1) bsums[blockIdx.x] = s[tid];
}

__global__ void k_scan2(int* __restrict__ bsums, int nb) {
    __shared__ int s[512];
    int tid = threadIdx.x;
    int v = (tid < nb) ? bsums[tid] : 0;
    s[tid] = v;
    __syncthreads();
    for (int o = 1; o < 512; o <<= 1) {
        int t = (tid >= o) ? s[tid - o] : 0;
        __syncthreads();
        s[tid] += t;
        __syncthreads();
    }
    if (tid < nb) bsums[tid] = s[tid] - v;    // exclusive
}

__global__ void k_scan3(int* __restrict__ off, int* __restrict__ cur,
                        const int* __restrict__ bsums, int n) {
    int i = blockIdx.x * SCAN_B + threadIdx.x;
    if (i < n) {
        int o = off[i] + bsums[blockIdx.x];
        off[i] = o;
        cur[i] = o;
    }
}

// ---------------- CSR fill: slot per edge, store (row, norm-weight) ----------------
__global__ void k_fill(const int* __restrict__ row, const int* __restrict__ col,
                       const float* __restrict__ ew, const float* __restrict__ dinv,
                       int* __restrict__ cur, int* __restrict__ csr_r,
                       float* __restrict__ csr_w, int E) {
    int e = blockIdx.x * blockDim.x + threadIdx.x;
    if (e >= E) return;
    int r = row[e], c = col[e];
    int p = atomicAdd(&cur[c], 1);
    csr_r[p] = r;
    csr_w[p] = dinv[r] * ew[e] * dinv[c];
}

// ---------------- atom encoder ----------------
__global__ void k_atom(const int* __restrict__ x, const float* __restrict__ at,
                       float* __restrict__ h, int n) {
    int node = blockIdx.x * 2 + (threadIdx.x >> 7);
    int d = threadIdx.x & 127;
    if (node >= n) return;
    const int* xr = x + node * 9;
    float s = 0.f;
#pragma unroll
    for (int f = 0; f < 9; ++f)
        s += at[(xr[f] + f * 64) * D + d];
    h[(long)node * D + d] = s;
}

// ---------------- matmul: out[n,:] = (RELU? max(h,0):h) @ W ----------------
#define KC 64
template <bool RELU>
__global__ __launch_bounds__(256) void k_matmul(const float* __restrict__ h,
                                                const float* __restrict__ W,
                                                float* __restrict__ out, int n) {
    __shared__ float hsT[KC * 129];
    __shared__ float Ws[KC * 128];
    const int tid = threadIdx.x;
    const int tr = tid >> 4;
    const int tc = tid & 15;
    const int r0 = tr * 8, c0 = tc * 8;
    const long row0 = (long)blockIdx.x * 128;
    float acc[8][8] = {};
    for (int kc = 0; kc < D; kc += KC) {
        for (int i = tid; i < 128 * (KC / 4); i += 256) {
            int r = i >> 4;
            int k4 = i & 15;
            long row = row0 + r;
            float4 v = make_float4(0.f, 0.f, 0.f, 0.f);
            if (row < n) v = *(const float4*)(h + row * D + kc + k4 * 4);
            if (RELU) {
                v.x = fmaxf(v.x, 0.f); v.y = fmaxf(v.y, 0.f);
                v.z = fmaxf(v.z, 0.f); v.w = fmaxf(v.w, 0.f);
            }
            int kb = k4 * 4;
            hsT[(kb + 0) * 129 + r] = v.x;
            hsT[(kb + 1) * 129 + r] = v.y;
            hsT[(kb + 2) * 129 + r] = v.z;
            hsT[(kb + 3) * 129 + r] = v.w;
        }
        for (int i = tid; i < KC * 32; i += 256)
            ((float4*)Ws)[i] = *(const float4*)(W + (long)kc * D + i * 4);
        __syncthreads();
        for (int k = 0; k < KC; ++k) {
            float hv[8], wv[8];
#pragma unroll
            for (int j = 0; j < 8; ++j) hv[j] = hsT[k * 129 + r0 + j];
            float4 w0 = *(const float4*)(&Ws[k * 128 + c0]);
            float4 w1 = *(const float4*)(&Ws[k * 128 + c0 + 4]);
            wv[0] = w0.x; wv[1] = w0.y; wv[2] = w0.z; wv[3] = w0.w;
            wv[4] = w1.x; wv[5] = w1.y; wv[6] = w1.z; wv[7] = w1.w;
#pragma unroll
            for (int a = 0; a < 8; ++a)
#pragma unroll
                for (int b = 0; b < 8; ++b)
                    acc[a][b] += hv[a] * wv[b];
        }
        __syncthreads();
    }
#pragma unroll
    for (int a = 0; a < 8; ++a) {
        long row = row0 + r0 + a;
        if (row < n) {
            *(float4*)(out + row * D + c0) =
                make_float4(acc[a][0], acc[a][1], acc[a][2], acc[a][3]);
            *(float4*)(out + row * D + c0 + 4) =
                make_float4(acc[a][4], acc[a][5], acc[a][6], acc[a][7]);
        }
    }
}

// ---------------- gather: out[c] = bias + hW[c]*dinv[c]^2 + sum_in hW[r]*w ----------------
__global__ void k_gather(const float* __restrict__ hW, const int* __restrict__ off,
                         const int* __restrict__ cnt, const int* __restrict__ csr_r,
                         const float* __restrict__ csr_w, const float* __restrict__ bias,
                         const float* __restrict__ dinv, float* __restrict__ out, int n) {
    int node = blockIdx.x * 4 + (threadIdx.x >> 6);
    int lane = threadIdx.x & 63;
    if (node >= n) return;
    int o = off[node];
    int c = cnt[node];
    float di = dinv[node];
    float2 h2 = *(const float2*)(hW + (long)node * D + lane * 2);
    float ax = h2.x * di * di;
    float ay = h2.y * di * di;
    int k = 0;
    for (; k + 2 <= c; k += 2) {
        int r0 = csr_r[o + k], r1 = csr_r[o + k + 1];
        float w0 = csr_w[o + k], w1 = csr_w[o + k + 1];
        float2 v0 = *(const float2*)(hW + (long)r0 * D + lane * 2);
        float2 v1 = *(const float2*)(hW + (long)r1 * D + lane * 2);
        ax += v0.x * w0 + v1.x * w1;
        ay += v0.y * w0 + v1.y * w1;
    }
    if (k < c) {
        int r0 = csr_r[o + k];
        float w0 = csr_w[o + k];
        float2 v0 = *(const float2*)(hW + (long)r0 * D + lane * 2);
        ax += v0.x * w0;
        ay += v0.y * w0;
    }
    float2 b2 = *(const float2*)(bias + lane * 2);
    ax += b2.x;
    ay += b2.y;
    *(float2*)(out + (long)node * D + lane * 2) = make_float2(ax, ay);
}

// ---------------- final: sigmoid(h @ lin_W + lin_b) ----------------
__global__ void k_final(const float* __restrict__ h, const float* __restrict__ linW,
                        const float* __restrict__ linb, float* __restrict__ out, int n) {
    long gt = (long)blockIdx.x * blockDim.x + threadIdx.x;
    int node = (int)(gt >> 6);
    int lane = threadIdx.x & 63;
    if (node >= n) return;
    float2 hv = *(const float2*)(h + (long)node * D + lane * 2);
    float2 wv = *(const float2*)(linW + lane * 2);
    float s = hv.x * wv.x + hv.y * wv.y;
#pragma unroll
    for (int off = 32; off; off >>= 1) s += __shfl_down(s, off);
    if (lane == 0) out[node] = 1.f / (1.f + expf(-(s + linb[0])));
}

extern "C" void kernel_launch(void* const* d_in, const int* in_sizes, int n_in,
                              void* d_out, int out_size, void* d_ws, size_t ws_size,
                              hipStream_t stream) {
    const int* x          = (const int*)d_in[0];
    const int* edge_index = (const int*)d_in[1];
    const int* edge_attr  = (const int*)d_in[2];
    const float* atom_table = (const float*)d_in[3];
    const float* bond_table = (const float*)d_in[4];
    const float* W1 = (const float*)d_in[5];
    const float* b1 = (const float*)d_in[6];
    const float* W2 = (const float*)d_in[7];
    const float* b2 = (const float*)d_in[8];
    const float* lin_W = (const float*)d_in[9];
    const float* lin_b = (const float*)d_in[10];
    float* out = (float*)d_out;

    const int N = in_sizes[0] / 9;
    const int E = in_sizes[1] / 2;
    const int* row = edge_index;      // sources
    const int* col = edge_index + E;  // destinations

    float* ws = (float*)d_ws;
    float* ew    = ws;                        // E
    float* dinv  = ew + E;                    // N
    int*   cnt   = (int*)(dinv + N);          // N
    int*   off   = cnt + N;                   // N
    int*   cur   = off + N;                   // N
    int*   bsums = cur + N;                   // 512
    int*   csr_r = bsums + 512;               // E
    float* csr_w = (float*)(csr_r + E);       // E
    float* bufA  = csr_w + E;                 // N*D
    float* bufB  = bufA + (long)N * D;        // N*D

    const int nb = (N + SCAN_B - 1) / SCAN_B;
    const int egrid = (E + 255) / 256;
    const int ngrid = (N + 255) / 256;

    // graph prep: degrees, edge weights, CSR by destination
    k_init<<<ngrid, 256, 0, stream>>>(dinv, cnt, N);
    k_edge_w<<<egrid, 256, 0, stream>>>(edge_attr, bond_table, col, ew, dinv, cnt, E);
    k_dinv<<<ngrid, 256, 0, stream>>>(dinv, N);
    k_scan1<<<nb, SCAN_B, 0, stream>>>(cnt, off, bsums, N);
    k_scan2<<<1, 512, 0, stream>>>(bsums, nb);
    k_scan3<<<nb, SCAN_B, 0, stream>>>(off, cur, bsums, N);
    k_fill<<<egrid, 256, 0, stream>>>(row, col, ew, dinv, cur, csr_r, csr_w, E);

    // atom encoder -> bufA
    k_atom<<<(N + 1) / 2, 256, 0, stream>>>(x, atom_table, bufA, N);

    // layer 1
    int mm_grid = (N + 127) / 128;
    k_matmul<false><<<mm_grid, 256, 0, stream>>>(bufA, W1, bufB, N);
    k_gather<<<(N + 3) / 4, 256, 0, stream>>>(bufB, off, cnt, csr_r, csr_w, b1, dinv, bufA, N);

    // layer 2 (relu fused into matmul load)
    k_matmul<true><<<mm_grid, 256, 0, stream>>>(bufA, W2, bufB, N);
    k_gather<<<(N + 3) / 4, 256, 0, stream>>>(bufB, off, cnt, csr_r, csr_w, b2, dinv, bufA, N);

    // final linear + sigmoid
    k_final<<<(N + 3) / 4, 256, 0, stream>>>(bufA, lin_W, lin_b, out, N);
}

// Round 3
// 274.405 us; speedup vs baseline: 8.1561x; 1.4849x over previous
//
#include <hip/hip_runtime.h>

#define D 128
typedef __attribute__((ext_vector_type(8))) short short8v;
typedef __attribute__((ext_vector_type(4))) float f32x4;

__device__ __forceinline__ float bf2f(unsigned short u) {
    union { unsigned int i; float f; } v; v.i = ((unsigned int)u) << 16; return v.f;
}
__device__ __forceinline__ unsigned short f2bf(float f) {
    union { float f; unsigned int i; } v; v.f = f;
    unsigned int r = v.i + 0x7FFF + ((v.i >> 16) & 1);
    return (unsigned short)(r >> 16);
}

// ---------------- init: deg=1 (self loop), cnt=0 ----------------
__global__ void k_init(float* __restrict__ deg, int* __restrict__ cnt, int n) {
    int i = blockIdx.x * blockDim.x + threadIdx.x;
    if (i < n) { deg[i] = 1.0f; cnt[i] = 0; }
}

// ---------------- edge weight + degree + in-degree count ----------------
__global__ void k_edge_w(const int* __restrict__ ea, const float* __restrict__ bt,
                         const int* __restrict__ col, float* __restrict__ ew,
                         float* __restrict__ deg, int* __restrict__ cnt, int E) {
    int e = blockIdx.x * blockDim.x + threadIdx.x;
    if (e >= E) return;
    float w = bt[ea[3 * e + 0]] + bt[16 + ea[3 * e + 1]] + bt[32 + ea[3 * e + 2]];
    ew[e] = w;
    int c = col[e];
    atomicAdd(&deg[c], w);
    atomicAdd(&cnt[c], 1);
}

__global__ void k_dinv(float* __restrict__ deg, int n) {
    int i = blockIdx.x * blockDim.x + threadIdx.x;
    if (i < n) {
        float d = deg[i];
        deg[i] = d > 0.f ? rsqrtf(d) : 0.f;
    }
}

// ---------------- exclusive scan (3-phase) ----------------
#define SCAN_B 256
__global__ void k_scan1(const int* __restrict__ cnt, int* __restrict__ off,
                        int* __restrict__ bsums, int n) {
    __shared__ int s[SCAN_B];
    int tid = threadIdx.x;
    int i = blockIdx.x * SCAN_B + tid;
    int v = (i < n) ? cnt[i] : 0;
    s[tid] = v;
    __syncthreads();
    for (int o = 1; o < SCAN_B; o <<= 1) {
        int t = (tid >= o) ? s[tid - o] : 0;
        __syncthreads();
        s[tid] += t;
        __syncthreads();
    }
    if (i < n) off[i] = s[tid] - v;
    if (tid == SCAN_B - 1) bsums[blockIdx.x] = s[tid];
}

__global__ void k_scan2(int* __restrict__ bsums, int nb) {
    __shared__ int s[512];
    int tid = threadIdx.x;
    int v = (tid < nb) ? bsums[tid] : 0;
    s[tid] = v;
    __syncthreads();
    for (int o = 1; o < 512; o <<= 1) {
        int t = (tid >= o) ? s[tid - o] : 0;
        __syncthreads();
        s[tid] += t;
        __syncthreads();
    }
    if (tid < nb) bsums[tid] = s[tid] - v;
}

__global__ void k_scan3(int* __restrict__ off, int* __restrict__ cur,
                        const int* __restrict__ bsums, int n) {
    int i = blockIdx.x * SCAN_B + threadIdx.x;
    if (i < n) {
        int o = off[i] + bsums[blockIdx.x];
        off[i] = o;
        cur[i] = o;
    }
}

// ---------------- CSR fill ----------------
__global__ void k_fill(const int* __restrict__ row, const int* __restrict__ col,
                       const float* __restrict__ ew, const float* __restrict__ dinv,
                       int* __restrict__ cur, int* __restrict__ csr_r,
                       float* __restrict__ csr_w, int E) {
    int e = blockIdx.x * blockDim.x + threadIdx.x;
    if (e >= E) return;
    int r = row[e], c = col[e];
    int p = atomicAdd(&cur[c], 1);
    csr_r[p] = r;
    csr_w[p] = dinv[r] * ew[e] * dinv[c];
}

// ---------------- W1 transpose + bf16 cvt: Wt[n][k] = W[k][n] ----------------
__global__ void k_wt(const float* __restrict__ W, unsigned short* __restrict__ Wt) {
    int idx = blockIdx.x * 256 + threadIdx.x;  // 16384
    int nn = idx >> 7, kk = idx & 127;
    Wt[idx] = f2bf(W[kk * D + nn]);
}

// ---------------- fold W2 @ lin_W -> w2l[128], w2l[128] = b2.lin + lin_b ----------------
__global__ void k_fuse(const float* __restrict__ W2, const float* __restrict__ b2,
                       const float* __restrict__ linW, const float* __restrict__ linb,
                       float* __restrict__ w2l) {
    int k = threadIdx.x;  // 128 threads
    float s = 0.f;
    for (int nn = 0; nn < D; ++nn) s += W2[k * D + nn] * linW[nn];
    w2l[k] = s;
    if (k == 0) {
        float cc = linb[0];
        for (int nn = 0; nn < D; ++nn) cc += b2[nn] * linW[nn];
        w2l[D] = cc;
    }
}

// ---------------- atom encoder -> bf16 ----------------
__global__ void k_atom(const int* __restrict__ x, const float* __restrict__ at,
                       unsigned short* __restrict__ h, int n) {
    int node = blockIdx.x * 8 + (threadIdx.x >> 5);
    int d0 = (threadIdx.x & 31) * 4;
    if (node >= n) return;
    const int* xr = x + node * 9;
    float sx = 0.f, sy = 0.f, sz = 0.f, sw = 0.f;
#pragma unroll
    for (int f = 0; f < 9; ++f) {
        float4 v = *(const float4*)(at + (long)(xr[f] + f * 64) * D + d0);
        sx += v.x; sy += v.y; sz += v.z; sw += v.w;
    }
    ushort4 o;
    o.x = f2bf(sx); o.y = f2bf(sy); o.z = f2bf(sz); o.w = f2bf(sw);
    *(ushort4*)(h + (long)node * D + d0) = o;
}

// ---------------- gather1: agg[c] = dinv^2*h[c] + sum_in w*h[r]  (bf16 in/out) ----------------
__global__ void k_gather1(const unsigned short* __restrict__ h, const int* __restrict__ off,
                          const int* __restrict__ cnt, const int* __restrict__ csr_r,
                          const float* __restrict__ csr_w, const float* __restrict__ dinv,
                          unsigned short* __restrict__ outh, int n) {
    int node = blockIdx.x * 4 + (threadIdx.x >> 6);
    int lane = threadIdx.x & 63;
    if (node >= n) return;
    int o = off[node], c = cnt[node];
    float di = dinv[node];
    ushort2 u = *(const ushort2*)(h + (long)node * D + lane * 2);
    float ax = bf2f(u.x) * di * di;
    float ay = bf2f(u.y) * di * di;
    int k = 0;
    for (; k + 2 <= c; k += 2) {
        int r0 = csr_r[o + k], r1 = csr_r[o + k + 1];
        float w0 = csr_w[o + k], w1 = csr_w[o + k + 1];
        ushort2 v0 = *(const ushort2*)(h + (long)r0 * D + lane * 2);
        ushort2 v1 = *(const ushort2*)(h + (long)r1 * D + lane * 2);
        ax += bf2f(v0.x) * w0 + bf2f(v1.x) * w1;
        ay += bf2f(v0.y) * w0 + bf2f(v1.y) * w1;
    }
    if (k < c) {
        int r0 = csr_r[o + k];
        float w0 = csr_w[o + k];
        ushort2 v0 = *(const ushort2*)(h + (long)r0 * D + lane * 2);
        ax += bf2f(v0.x) * w0;
        ay += bf2f(v0.y) * w0;
    }
    ushort2 ov;
    ov.x = f2bf(ax); ov.y = f2bf(ay);
    *(ushort2*)(outh + (long)node * D + lane * 2) = ov;
}

// ---------------- MFMA matmul: out = relu(A @ W1 + b1), bf16 in/out ----------------
// mfma_f32_16x16x32_bf16: A[m=l&15][k=8*(l>>4)+j]; B[k][n=l&15] via Wt[n][k];
// C: col=l&15, row=4*(l>>4)+reg  (verified layouts, learn_hip m89/m91)
__global__ __launch_bounds__(256) void k_mm1(const unsigned short* __restrict__ A,
                                             const unsigned short* __restrict__ Wt,
                                             const float* __restrict__ bias,
                                             unsigned short* __restrict__ out, int n) {
    const int tid = threadIdx.x;
    const int w = tid >> 6, l = tid & 63;
    const int lm = l & 15, lk = l >> 4;
    const long rbase = (long)blockIdx.x * 128 + w * 32;
    f32x4 acc[2][8] = {};
#pragma unroll
    for (int kc = 0; kc < 4; ++kc) {
        short8v bfr[8];
#pragma unroll
        for (int ct = 0; ct < 8; ++ct)
            bfr[ct] = *(const short8v*)(Wt + (long)(ct * 16 + lm) * D + kc * 32 + lk * 8);
#pragma unroll
        for (int rt = 0; rt < 2; ++rt) {
            long r = rbase + rt * 16 + lm;
            if (r >= n) r = n - 1;
            short8v afr = *(const short8v*)(A + r * D + kc * 32 + lk * 8);
#pragma unroll
            for (int ct = 0; ct < 8; ++ct)
                acc[rt][ct] = __builtin_amdgcn_mfma_f32_16x16x32_bf16(afr, bfr[ct], acc[rt][ct], 0, 0, 0);
        }
    }
#pragma unroll
    for (int rt = 0; rt < 2; ++rt) {
#pragma unroll
        for (int ct = 0; ct < 8; ++ct) {
            int col = ct * 16 + lm;
            float b = bias[col];
#pragma unroll
            for (int j = 0; j < 4; ++j) {
                long r = rbase + rt * 16 + lk * 4 + j;
                if (r < n)
                    out[r * D + col] = f2bf(fmaxf(acc[rt][ct][j] + b, 0.f));
            }
        }
    }
}

// ---------------- gather2 + fused dot + sigmoid ----------------
__global__ void k_gather2(const unsigned short* __restrict__ h, const int* __restrict__ off,
                          const int* __restrict__ cnt, const int* __restrict__ csr_r,
                          const float* __restrict__ csr_w, const float* __restrict__ dinv,
                          const float* __restrict__ w2l, float* __restrict__ out, int n) {
    int node = blockIdx.x * 4 + (threadIdx.x >> 6);
    int lane = threadIdx.x & 63;
    if (node >= n) return;
    int o = off[node], c = cnt[node];
    float di = dinv[node];
    ushort2 u = *(const ushort2*)(h + (long)node * D + lane * 2);
    float ax = bf2f(u.x) * di * di;
    float ay = bf2f(u.y) * di * di;
    int k = 0;
    for (; k + 2 <= c; k += 2) {
        int r0 = csr_r[o + k], r1 = csr_r[o + k + 1];
        float w0 = csr_w[o + k], w1 = csr_w[o + k + 1];
        ushort2 v0 = *(const ushort2*)(h + (long)r0 * D + lane * 2);
        ushort2 v1 = *(const ushort2*)(h + (long)r1 * D + lane * 2);
        ax += bf2f(v0.x) * w0 + bf2f(v1.x) * w1;
        ay += bf2f(v0.y) * w0 + bf2f(v1.y) * w1;
    }
    if (k < c) {
        int r0 = csr_r[o + k];
        float w0 = csr_w[o + k];
        ushort2 v0 = *(const ushort2*)(h + (long)r0 * D + lane * 2);
        ax += bf2f(v0.x) * w0;
        ay += bf2f(v0.y) * w0;
    }
    float2 wv = *(const float2*)(w2l + lane * 2);
    float s = ax * wv.x + ay * wv.y;
#pragma unroll
    for (int sh = 32; sh; sh >>= 1) s += __shfl_down(s, sh);
    if (lane == 0) out[node] = 1.f / (1.f + expf(-(s + w2l[D])));
}

extern "C" void kernel_launch(void* const* d_in, const int* in_sizes, int n_in,
                              void* d_out, int out_size, void* d_ws, size_t ws_size,
                              hipStream_t stream) {
    const int* x          = (const int*)d_in[0];
    const int* edge_index = (const int*)d_in[1];
    const int* edge_attr  = (const int*)d_in[2];
    const float* atom_table = (const float*)d_in[3];
    const float* bond_table = (const float*)d_in[4];
    const float* W1 = (const float*)d_in[5];
    const float* b1 = (const float*)d_in[6];
    const float* W2 = (const float*)d_in[7];
    const float* b2 = (const float*)d_in[8];
    const float* lin_W = (const float*)d_in[9];
    const float* lin_b = (const float*)d_in[10];
    float* out = (float*)d_out;

    const int N = in_sizes[0] / 9;
    const int E = in_sizes[1] / 2;
    const int* row = edge_index;      // sources
    const int* col = edge_index + E;  // destinations

    float* ws = (float*)d_ws;
    float* ew    = ws;                         // E
    float* dinv  = ew + E;                     // N
    int*   cnt   = (int*)(dinv + N);           // N
    int*   off   = cnt + N;                    // N
    int*   cur   = off + N;                    // N
    int*   bsums = cur + N;                    // 512
    int*   csr_r = bsums + 512;                // E
    float* csr_w = (float*)(csr_r + E);        // E
    float* w2l   = csr_w + E;                  // 132 (128 + c + pad)
    unsigned short* W1t = (unsigned short*)(w2l + 132);  // 16384
    unsigned short* hA  = W1t + 16384;                   // N*D bf16
    unsigned short* hB  = hA + (long)N * D;              // N*D bf16

    const int nb = (N + SCAN_B - 1) / SCAN_B;
    const int egrid = (E + 255) / 256;
    const int ngrid = (N + 255) / 256;

    // graph prep
    k_init<<<ngrid, 256, 0, stream>>>(dinv, cnt, N);
    k_edge_w<<<egrid, 256, 0, stream>>>(edge_attr, bond_table, col, ew, dinv, cnt, E);
    k_dinv<<<ngrid, 256, 0, stream>>>(dinv, N);
    k_scan1<<<nb, SCAN_B, 0, stream>>>(cnt, off, bsums, N);
    k_scan2<<<1, 512, 0, stream>>>(bsums, nb);
    k_scan3<<<nb, SCAN_B, 0, stream>>>(off, cur, bsums, N);
    k_fill<<<egrid, 256, 0, stream>>>(row, col, ew, dinv, cur, csr_r, csr_w, E);

    // weight prep
    k_wt<<<64, 256, 0, stream>>>(W1, W1t);
    k_fuse<<<1, 128, 0, stream>>>(W2, b2, lin_W, lin_b, w2l);

    // pipeline: atom -> hA; gather1 hA -> hB; mm1 hB -> hA; gather2 hA -> out
    k_atom<<<(N + 7) / 8, 256, 0, stream>>>(x, atom_table, hA, N);
    k_gather1<<<(N + 3) / 4, 256, 0, stream>>>(hA, off, cnt, csr_r, csr_w, dinv, hB, N);
    k_mm1<<<(N + 127) / 128, 256, 0, stream>>>(hB, W1t, b1, hA, N);
    k_gather2<<<(N + 3) / 4, 256, 0, stream>>>(hA, off, cnt, csr_r, csr_w, dinv, w2l, out, N);
}

// Round 4
// 228.547 us; speedup vs baseline: 9.7926x; 1.2007x over previous
//
#include <hip/hip_runtime.h>

#define D 128
typedef __attribute__((ext_vector_type(8))) short short8v;
typedef __attribute__((ext_vector_type(4))) float f32x4;

__device__ __forceinline__ float bf2f(unsigned short u) {
    union { unsigned int i; float f; } v; v.i = ((unsigned int)u) << 16; return v.f;
}
__device__ __forceinline__ unsigned short f2bf(float f) {
    union { float f; unsigned int i; } v; v.f = f;
    unsigned int r = v.i + 0x7FFF + ((v.i >> 16) & 1);
    return (unsigned short)(r >> 16);
}

// ---------------- edge pass: weight + histogram rank (ONE atomic per edge) ----------------
__global__ void k_edge_w(const int* __restrict__ ea, const float* __restrict__ bt,
                         const int* __restrict__ col, float* __restrict__ ew,
                         int* __restrict__ rank, int* __restrict__ cnt, int E) {
    int e = blockIdx.x * blockDim.x + threadIdx.x;
    if (e >= E) return;
    float w = bt[ea[3 * e + 0]] + bt[16 + ea[3 * e + 1]] + bt[32 + ea[3 * e + 2]];
    ew[e] = w;
    rank[e] = atomicAdd(&cnt[col[e]], 1);
}

// ---------------- exclusive scan (3-phase) ----------------
#define SCAN_B 256
__global__ void k_scan1(const int* __restrict__ cnt, int* __restrict__ off,
                        int* __restrict__ bsums, int n) {
    __shared__ int s[SCAN_B];
    int tid = threadIdx.x;
    int i = blockIdx.x * SCAN_B + tid;
    int v = (i < n) ? cnt[i] : 0;
    s[tid] = v;
    __syncthreads();
    for (int o = 1; o < SCAN_B; o <<= 1) {
        int t = (tid >= o) ? s[tid - o] : 0;
        __syncthreads();
        s[tid] += t;
        __syncthreads();
    }
    if (i < n) off[i] = s[tid] - v;
    if (tid == SCAN_B - 1) bsums[blockIdx.x] = s[tid];
}

__global__ void k_scan2(int* __restrict__ bsums, int nb) {
    __shared__ int s[512];
    int tid = threadIdx.x;
    int v = (tid < nb) ? bsums[tid] : 0;
    s[tid] = v;
    __syncthreads();
    for (int o = 1; o < 512; o <<= 1) {
        int t = (tid >= o) ? s[tid - o] : 0;
        __syncthreads();
        s[tid] += t;
        __syncthreads();
    }
    if (tid < nb) bsums[tid] = s[tid] - v;
}

__global__ void k_scan3(int* __restrict__ off, const int* __restrict__ bsums, int n) {
    int i = blockIdx.x * SCAN_B + threadIdx.x;
    if (i < n) off[i] += bsums[blockIdx.x];
}

// ---------------- CSR fill (NO atomics): slot = off[col] + rank ----------------
__global__ void k_fill(const int* __restrict__ row, const int* __restrict__ col,
                       const int* __restrict__ rank, const int* __restrict__ off,
                       const float* __restrict__ ew, int2* __restrict__ csr, int E) {
    int e = blockIdx.x * blockDim.x + threadIdx.x;
    if (e >= E) return;
    int c = col[e];
    int p = off[c] + rank[e];
    int2 v;
    v.x = row[e];
    v.y = __float_as_int(ew[e]);
    csr[p] = v;
}

// ---------------- degree from CSR -> dinv (no atomics) ----------------
__global__ void k_degdinv(const int2* __restrict__ csr, const int* __restrict__ off,
                          const int* __restrict__ cnt, float* __restrict__ dinv, int n) {
    int i = blockIdx.x * blockDim.x + threadIdx.x;
    if (i >= n) return;
    int o = off[i], c = cnt[i];
    float d = 1.0f;  // self loop
    for (int k = 0; k < c; ++k) d += __int_as_float(csr[o + k].y);
    dinv[i] = d > 0.f ? rsqrtf(d) : 0.f;
}

// ---------------- W1 transpose + bf16 cvt: Wt[n][k] = W[k][n] ----------------
__global__ void k_wt(const float* __restrict__ W, unsigned short* __restrict__ Wt) {
    int idx = blockIdx.x * 256 + threadIdx.x;  // 16384
    int nn = idx >> 7, kk = idx & 127;
    Wt[idx] = f2bf(W[kk * D + nn]);
}

// ---------------- fold W2 @ lin_W -> w2l[128], w2l[128]=b2.lin+lin_b ----------------
__global__ void k_fuse(const float* __restrict__ W2, const float* __restrict__ b2,
                       const float* __restrict__ linW, const float* __restrict__ linb,
                       float* __restrict__ w2l) {
    int k = threadIdx.x;  // 128 threads
    float s = 0.f;
    for (int nn = 0; nn < D; ++nn) s += W2[k * D + nn] * linW[nn];
    w2l[k] = s;
    if (k == 0) {
        float cc = linb[0];
        for (int nn = 0; nn < D; ++nn) cc += b2[nn] * linW[nn];
        w2l[D] = cc;
    }
}

// ---------------- atom encoder -> bf16 ----------------
__global__ void k_atom(const int* __restrict__ x, const float* __restrict__ at,
                       unsigned short* __restrict__ h, int n) {
    int node = blockIdx.x * 8 + (threadIdx.x >> 5);
    int d0 = (threadIdx.x & 31) * 4;
    if (node >= n) return;
    const int* xr = x + node * 9;
    float sx = 0.f, sy = 0.f, sz = 0.f, sw = 0.f;
#pragma unroll
    for (int f = 0; f < 9; ++f) {
        float4 v = *(const float4*)(at + (long)(xr[f] + f * 64) * D + d0);
        sx += v.x; sy += v.y; sz += v.z; sw += v.w;
    }
    ushort4 o;
    o.x = f2bf(sx); o.y = f2bf(sy); o.z = f2bf(sz); o.w = f2bf(sw);
    *(ushort4*)(h + (long)node * D + d0) = o;
}

// ---------------- gather1: agg[c] = dinv^2*h[c] + sum_in dinv[r]*w*dinv[c]*h[r] ----------------
__global__ void k_gather1(const unsigned short* __restrict__ h, const int* __restrict__ off,
                          const int* __restrict__ cnt, const int2* __restrict__ csr,
                          const float* __restrict__ dinv, unsigned short* __restrict__ outh,
                          int n) {
    int node = blockIdx.x * 4 + (threadIdx.x >> 6);
    int lane = threadIdx.x & 63;
    if (node >= n) return;
    int o = off[node], c = cnt[node];
    float dic = dinv[node];
    ushort2 u = *(const ushort2*)(h + (long)node * D + lane * 2);
    float ax = bf2f(u.x) * dic * dic;
    float ay = bf2f(u.y) * dic * dic;
    int k = 0;
    for (; k + 2 <= c; k += 2) {
        int2 p0 = csr[o + k], p1 = csr[o + k + 1];
        float w0 = dinv[p0.x] * __int_as_float(p0.y) * dic;
        float w1 = dinv[p1.x] * __int_as_float(p1.y) * dic;
        ushort2 v0 = *(const ushort2*)(h + (long)p0.x * D + lane * 2);
        ushort2 v1 = *(const ushort2*)(h + (long)p1.x * D + lane * 2);
        ax += bf2f(v0.x) * w0 + bf2f(v1.x) * w1;
        ay += bf2f(v0.y) * w0 + bf2f(v1.y) * w1;
    }
    if (k < c) {
        int2 p0 = csr[o + k];
        float w0 = dinv[p0.x] * __int_as_float(p0.y) * dic;
        ushort2 v0 = *(const ushort2*)(h + (long)p0.x * D + lane * 2);
        ax += bf2f(v0.x) * w0;
        ay += bf2f(v0.y) * w0;
    }
    ushort2 ov;
    ov.x = f2bf(ax); ov.y = f2bf(ay);
    *(ushort2*)(outh + (long)node * D + lane * 2) = ov;
}

// ---------------- MFMA matmul: out = relu(A @ W1 + b1), bf16 in/out ----------------
__global__ __launch_bounds__(256) void k_mm1(const unsigned short* __restrict__ A,
                                             const unsigned short* __restrict__ Wt,
                                             const float* __restrict__ bias,
                                             unsigned short* __restrict__ out, int n) {
    const int tid = threadIdx.x;
    const int w = tid >> 6, l = tid & 63;
    const int lm = l & 15, lk = l >> 4;
    const long rbase = (long)blockIdx.x * 128 + w * 32;
    f32x4 acc[2][8] = {};
#pragma unroll
    for (int kc = 0; kc < 4; ++kc) {
        short8v bfr[8];
#pragma unroll
        for (int ct = 0; ct < 8; ++ct)
            bfr[ct] = *(const short8v*)(Wt + (long)(ct * 16 + lm) * D + kc * 32 + lk * 8);
#pragma unroll
        for (int rt = 0; rt < 2; ++rt) {
            long r = rbase + rt * 16 + lm;
            if (r >= n) r = n - 1;
            short8v afr = *(const short8v*)(A + r * D + kc * 32 + lk * 8);
#pragma unroll
            for (int ct = 0; ct < 8; ++ct)
                acc[rt][ct] = __builtin_amdgcn_mfma_f32_16x16x32_bf16(afr, bfr[ct], acc[rt][ct], 0, 0, 0);
        }
    }
#pragma unroll
    for (int rt = 0; rt < 2; ++rt) {
#pragma unroll
        for (int ct = 0; ct < 8; ++ct) {
            int col = ct * 16 + lm;
            float b = bias[col];
#pragma unroll
            for (int j = 0; j < 4; ++j) {
                long r = rbase + rt * 16 + lk * 4 + j;
                if (r < n)
                    out[r * D + col] = f2bf(fmaxf(acc[rt][ct][j] + b, 0.f));
            }
        }
    }
}

// ---------------- gather2 + fused dot + sigmoid ----------------
__global__ void k_gather2(const unsigned short* __restrict__ h, const int* __restrict__ off,
                          const int* __restrict__ cnt, const int2* __restrict__ csr,
                          const float* __restrict__ dinv, const float* __restrict__ w2l,
                          float* __restrict__ out, int n) {
    int node = blockIdx.x * 4 + (threadIdx.x >> 6);
    int lane = threadIdx.x & 63;
    if (node >= n) return;
    int o = off[node], c = cnt[node];
    float dic = dinv[node];
    ushort2 u = *(const ushort2*)(h + (long)node * D + lane * 2);
    float ax = bf2f(u.x) * dic * dic;
    float ay = bf2f(u.y) * dic * dic;
    int k = 0;
    for (; k + 2 <= c; k += 2) {
        int2 p0 = csr[o + k], p1 = csr[o + k + 1];
        float w0 = dinv[p0.x] * __int_as_float(p0.y) * dic;
        float w1 = dinv[p1.x] * __int_as_float(p1.y) * dic;
        ushort2 v0 = *(const ushort2*)(h + (long)p0.x * D + lane * 2);
        ushort2 v1 = *(const ushort2*)(h + (long)p1.x * D + lane * 2);
        ax += bf2f(v0.x) * w0 + bf2f(v1.x) * w1;
        ay += bf2f(v0.y) * w0 + bf2f(v1.y) * w1;
    }
    if (k < c) {
        int2 p0 = csr[o + k];
        float w0 = dinv[p0.x] * __int_as_float(p0.y) * dic;
        ushort2 v0 = *(const ushort2*)(h + (long)p0.x * D + lane * 2);
        ax += bf2f(v0.x) * w0;
        ay += bf2f(v0.y) * w0;
    }
    float2 wv = *(const float2*)(w2l + lane * 2);
    float s = ax * wv.x + ay * wv.y;
#pragma unroll
    for (int sh = 32; sh; sh >>= 1) s += __shfl_down(s, sh);
    if (lane == 0) out[node] = 1.f / (1.f + expf(-(s + w2l[D])));
}

extern "C" void kernel_launch(void* const* d_in, const int* in_sizes, int n_in,
                              void* d_out, int out_size, void* d_ws, size_t ws_size,
                              hipStream_t stream) {
    const int* x          = (const int*)d_in[0];
    const int* edge_index = (const int*)d_in[1];
    const int* edge_attr  = (const int*)d_in[2];
    const float* atom_table = (const float*)d_in[3];
    const float* bond_table = (const float*)d_in[4];
    const float* W1 = (const float*)d_in[5];
    const float* b1 = (const float*)d_in[6];
    const float* W2 = (const float*)d_in[7];
    const float* b2 = (const float*)d_in[8];
    const float* lin_W = (const float*)d_in[9];
    const float* lin_b = (const float*)d_in[10];
    float* out = (float*)d_out;

    const int N = in_sizes[0] / 9;
    const int E = in_sizes[1] / 2;
    const int* row = edge_index;      // sources
    const int* col = edge_index + E;  // destinations

    float* ws = (float*)d_ws;
    float* ew    = ws;                          // E
    float* dinv  = ew + E;                      // N
    int*   cnt   = (int*)(dinv + N);            // N
    int*   off   = cnt + N;                     // N
    int*   rank  = off + N;                     // E
    int*   bsums = rank + E;                    // 512
    int2*  csr   = (int2*)(bsums + 512);        // E int2 (8B aligned: offset even)
    float* w2l   = (float*)(csr + E);           // 132
    unsigned short* W1t = (unsigned short*)(w2l + 132);  // 16384
    unsigned short* hA  = W1t + 16384;                   // N*D bf16
    unsigned short* hB  = hA + (long)N * D;              // N*D bf16

    const int nb = (N + SCAN_B - 1) / SCAN_B;
    const int egrid = (E + 255) / 256;
    const int ngrid = (N + 255) / 256;

    // graph prep
    hipMemsetAsync(cnt, 0, (size_t)N * sizeof(int), stream);
    k_edge_w<<<egrid, 256, 0, stream>>>(edge_attr, bond_table, col, ew, rank, cnt, E);
    k_scan1<<<nb, SCAN_B, 0, stream>>>(cnt, off, bsums, N);
    k_scan2<<<1, 512, 0, stream>>>(bsums, nb);
    k_scan3<<<nb, SCAN_B, 0, stream>>>(off, bsums, N);
    k_fill<<<egrid, 256, 0, stream>>>(row, col, rank, off, ew, csr, E);
    k_degdinv<<<ngrid, 256, 0, stream>>>(csr, off, cnt, dinv, N);

    // weight prep
    k_wt<<<64, 256, 0, stream>>>(W1, W1t);
    k_fuse<<<1, 128, 0, stream>>>(W2, b2, lin_W, lin_b, w2l);

    // pipeline: atom -> hA; gather1 hA -> hB; mm1 hB -> hA; gather2 hA -> out
    k_atom<<<(N + 7) / 8, 256, 0, stream>>>(x, atom_table, hA, N);
    k_gather1<<<(N + 3) / 4, 256, 0, stream>>>(hA, off, cnt, csr, dinv, hB, N);
    k_mm1<<<(N + 127) / 128, 256, 0, stream>>>(hB, W1t, b1, hA, N);
    k_gather2<<<(N + 3) / 4, 256, 0, stream>>>(hA, off, cnt, csr, dinv, w2l, out, N);
}

// Round 5
// 163.985 us; speedup vs baseline: 13.6480x; 1.3937x over previous
//
#include <hip/hip_runtime.h>

#define D 128
typedef __attribute__((ext_vector_type(8))) short short8v;
typedef __attribute__((ext_vector_type(4))) float f32x4;

__device__ __forceinline__ float bf2f(unsigned short u) {
    union { unsigned int i; float f; } v; v.i = ((unsigned int)u) << 16; return v.f;
}
__device__ __forceinline__ unsigned short f2bf(float f) {
    union { float f; unsigned int i; } v; v.f = f;
    unsigned int r = v.i + 0x7FFF + ((v.i >> 16) & 1);
    return (unsigned short)(r >> 16);
}

// ---------------- edge pass: weight + histogram rank (ONE atomic per edge) ----------------
__global__ void k_edge_w(const int* __restrict__ ea, const float* __restrict__ bt,
                         const int* __restrict__ col, float* __restrict__ ew,
                         int* __restrict__ rank, int* __restrict__ cnt, int E) {
    int e = blockIdx.x * blockDim.x + threadIdx.x;
    if (e >= E) return;
    float w = bt[ea[3 * e + 0]] + bt[16 + ea[3 * e + 1]] + bt[32 + ea[3 * e + 2]];
    ew[e] = w;
    rank[e] = atomicAdd(&cnt[col[e]], 1);
}

// ---------------- exclusive scan (3-phase) ----------------
#define SCAN_B 256
__global__ void k_scan1(const int* __restrict__ cnt, int* __restrict__ off,
                        int* __restrict__ bsums, int n) {
    __shared__ int s[SCAN_B];
    int tid = threadIdx.x;
    int i = blockIdx.x * SCAN_B + tid;
    int v = (i < n) ? cnt[i] : 0;
    s[tid] = v;
    __syncthreads();
    for (int o = 1; o < SCAN_B; o <<= 1) {
        int t = (tid >= o) ? s[tid - o] : 0;
        __syncthreads();
        s[tid] += t;
        __syncthreads();
    }
    if (i < n) off[i] = s[tid] - v;
    if (tid == SCAN_B - 1) bsums[blockIdx.x] = s[tid];
}

__global__ void k_scan2(int* __restrict__ bsums, int nb) {
    __shared__ int s[512];
    int tid = threadIdx.x;
    int v = (tid < nb) ? bsums[tid] : 0;
    s[tid] = v;
    __syncthreads();
    for (int o = 1; o < 512; o <<= 1) {
        int t = (tid >= o) ? s[tid - o] : 0;
        __syncthreads();
        s[tid] += t;
        __syncthreads();
    }
    if (tid < nb) bsums[tid] = s[tid] - v;
}

__global__ void k_scan3(int* __restrict__ off, const int* __restrict__ bsums, int n) {
    int i = blockIdx.x * SCAN_B + threadIdx.x;
    if (i < n) off[i] += bsums[blockIdx.x];
}

// ---------------- CSR fill (NO atomics): slot = off[col] + rank ----------------
__global__ void k_fill(const int* __restrict__ row, const int* __restrict__ col,
                       const int* __restrict__ rank, const int* __restrict__ off,
                       const float* __restrict__ ew, int2* __restrict__ csr, int E) {
    int e = blockIdx.x * blockDim.x + threadIdx.x;
    if (e >= E) return;
    int c = col[e];
    int p = off[c] + rank[e];
    int2 v;
    v.x = row[e];
    v.y = __float_as_int(ew[e]);
    csr[p] = v;
}

// ---------------- degree from CSR -> dinv (no atomics) ----------------
__global__ void k_degdinv(const int2* __restrict__ csr, const int* __restrict__ off,
                          const int* __restrict__ cnt, float* __restrict__ dinv, int n) {
    int i = blockIdx.x * blockDim.x + threadIdx.x;
    if (i >= n) return;
    int o = off[i], c = cnt[i];
    float d = 1.0f;  // self loop
    for (int k = 0; k < c; ++k) d += __int_as_float(csr[o + k].y);
    dinv[i] = d > 0.f ? rsqrtf(d) : 0.f;
}

// ---------------- W1 transpose + bf16 cvt: Wt[n][k] = W[k][n] ----------------
__global__ void k_wt(const float* __restrict__ W, unsigned short* __restrict__ Wt) {
    int idx = blockIdx.x * 256 + threadIdx.x;  // 16384
    int nn = idx >> 7, kk = idx & 127;
    Wt[idx] = f2bf(W[kk * D + nn]);
}

// ---------------- fold W2 @ lin_W -> w2l[128], w2l[128]=b2.lin+lin_b ----------------
__global__ void k_fuse(const float* __restrict__ W2, const float* __restrict__ b2,
                       const float* __restrict__ linW, const float* __restrict__ linb,
                       float* __restrict__ w2l) {
    int k = threadIdx.x;  // 128 threads
    float s = 0.f;
    for (int nn = 0; nn < D; ++nn) s += W2[k * D + nn] * linW[nn];
    w2l[k] = s;
    if (k == 0) {
        float cc = linb[0];
        for (int nn = 0; nn < D; ++nn) cc += b2[nn] * linW[nn];
        w2l[D] = cc;
    }
}

// ---------------- atom encoder -> bf16 ----------------
__global__ void k_atom(const int* __restrict__ x, const float* __restrict__ at,
                       unsigned short* __restrict__ h, int n) {
    int node = blockIdx.x * 8 + (threadIdx.x >> 5);
    int d0 = (threadIdx.x & 31) * 4;
    if (node >= n) return;
    const int* xr = x + node * 9;
    float sx = 0.f, sy = 0.f, sz = 0.f, sw = 0.f;
#pragma unroll
    for (int f = 0; f < 9; ++f) {
        float4 v = *(const float4*)(at + (long)(xr[f] + f * 64) * D + d0);
        sx += v.x; sy += v.y; sz += v.z; sw += v.w;
    }
    ushort4 o;
    o.x = f2bf(sx); o.y = f2bf(sy); o.z = f2bf(sz); o.w = f2bf(sw);
    *(ushort4*)(h + (long)node * D + d0) = o;
}

// ---------------- gather1: agg[c] = dinv^2*h[c] + sum_in dinv[r]*w*dinv[c]*h[r] ----------------
// unroll-4 software pipeline: ~4 independent 256B row-gathers in flight per wave
__global__ void k_gather1(const unsigned short* __restrict__ h, const int* __restrict__ off,
                          const int* __restrict__ cnt, const int2* __restrict__ csr,
                          const float* __restrict__ dinv, unsigned short* __restrict__ outh,
                          int n) {
    int node = blockIdx.x * 4 + (threadIdx.x >> 6);
    int lane = threadIdx.x & 63;
    if (node >= n) return;
    int o = off[node], c = cnt[node];
    float dic = dinv[node];
    ushort2 u = *(const ushort2*)(h + (long)node * D + lane * 2);
    float ax0 = bf2f(u.x) * dic * dic;
    float ay0 = bf2f(u.y) * dic * dic;
    float ax1 = 0.f, ay1 = 0.f;
    int k = 0;
    for (; k + 4 <= c; k += 4) {
        int2 p0 = csr[o + k], p1 = csr[o + k + 1], p2 = csr[o + k + 2], p3 = csr[o + k + 3];
        float w0 = dinv[p0.x] * __int_as_float(p0.y) * dic;
        float w1 = dinv[p1.x] * __int_as_float(p1.y) * dic;
        float w2 = dinv[p2.x] * __int_as_float(p2.y) * dic;
        float w3 = dinv[p3.x] * __int_as_float(p3.y) * dic;
        ushort2 v0 = *(const ushort2*)(h + (long)p0.x * D + lane * 2);
        ushort2 v1 = *(const ushort2*)(h + (long)p1.x * D + lane * 2);
        ushort2 v2 = *(const ushort2*)(h + (long)p2.x * D + lane * 2);
        ushort2 v3 = *(const ushort2*)(h + (long)p3.x * D + lane * 2);
        ax0 += bf2f(v0.x) * w0 + bf2f(v1.x) * w1;
        ay0 += bf2f(v0.y) * w0 + bf2f(v1.y) * w1;
        ax1 += bf2f(v2.x) * w2 + bf2f(v3.x) * w3;
        ay1 += bf2f(v2.y) * w2 + bf2f(v3.y) * w3;
    }
    for (; k < c; ++k) {
        int2 p0 = csr[o + k];
        float w0 = dinv[p0.x] * __int_as_float(p0.y) * dic;
        ushort2 v0 = *(const ushort2*)(h + (long)p0.x * D + lane * 2);
        ax0 += bf2f(v0.x) * w0;
        ay0 += bf2f(v0.y) * w0;
    }
    ushort2 ov;
    ov.x = f2bf(ax0 + ax1); ov.y = f2bf(ay0 + ay1);
    *(ushort2*)(outh + (long)node * D + lane * 2) = ov;
}

// ---------------- MFMA matmul + fused scalar projection ----------------
// s[r] = relu(A@W1 + b1)[r] . w2l   -- h1 never materialized
__global__ __launch_bounds__(256) void k_mm1(const unsigned short* __restrict__ A,
                                             const unsigned short* __restrict__ Wt,
                                             const float* __restrict__ bias,
                                             const float* __restrict__ w2l,
                                             float* __restrict__ sOut, int n) {
    const int tid = threadIdx.x;
    const int w = tid >> 6, l = tid & 63;
    const int lm = l & 15, lk = l >> 4;
    const long rbase = (long)blockIdx.x * 128 + w * 32;
    f32x4 acc[2][8] = {};
#pragma unroll
    for (int kc = 0; kc < 4; ++kc) {
        short8v bfr[8];
#pragma unroll
        for (int ct = 0; ct < 8; ++ct)
            bfr[ct] = *(const short8v*)(Wt + (long)(ct * 16 + lm) * D + kc * 32 + lk * 8);
#pragma unroll
        for (int rt = 0; rt < 2; ++rt) {
            long r = rbase + rt * 16 + lm;
            if (r >= n) r = n - 1;
            short8v afr = *(const short8v*)(A + r * D + kc * 32 + lk * 8);
#pragma unroll
            for (int ct = 0; ct < 8; ++ct)
                acc[rt][ct] = __builtin_amdgcn_mfma_f32_16x16x32_bf16(afr, bfr[ct], acc[rt][ct], 0, 0, 0);
        }
    }
    float bcol[8], wcol[8];
#pragma unroll
    for (int ct = 0; ct < 8; ++ct) {
        bcol[ct] = bias[ct * 16 + lm];
        wcol[ct] = w2l[ct * 16 + lm];
    }
    float p[2][4] = {};
#pragma unroll
    for (int rt = 0; rt < 2; ++rt)
#pragma unroll
        for (int ct = 0; ct < 8; ++ct)
#pragma unroll
            for (int j = 0; j < 4; ++j)
                p[rt][j] += fmaxf(acc[rt][ct][j] + bcol[ct], 0.f) * wcol[ct];
    // reduce across the 16 lanes (lm) sharing each row group
#pragma unroll
    for (int m = 1; m < 16; m <<= 1) {
#pragma unroll
        for (int rt = 0; rt < 2; ++rt)
#pragma unroll
            for (int j = 0; j < 4; ++j)
                p[rt][j] += __shfl_xor(p[rt][j], m);
    }
    if (lm == 0) {
#pragma unroll
        for (int rt = 0; rt < 2; ++rt)
#pragma unroll
            for (int j = 0; j < 4; ++j) {
                long r = rbase + rt * 16 + lk * 4 + j;
                if (r < n) sOut[r] = p[rt][j];
            }
    }
}

// ---------------- gather2 scalar: out[v] = sigmoid(dic^2 s[v] + sum w*s[r] + c) ----------------
__global__ void k_gather2s(const float* __restrict__ s, const int* __restrict__ off,
                           const int* __restrict__ cnt, const int2* __restrict__ csr,
                           const float* __restrict__ dinv, const float* __restrict__ w2l,
                           float* __restrict__ out, int n) {
    int v = blockIdx.x * blockDim.x + threadIdx.x;
    if (v >= n) return;
    int o = off[v], c = cnt[v];
    float dic = dinv[v];
    float a = s[v] * dic * dic;
    int k = 0;
    for (; k + 2 <= c; k += 2) {
        int2 p0 = csr[o + k], p1 = csr[o + k + 1];
        a += dinv[p0.x] * __int_as_float(p0.y) * dic * s[p0.x];
        a += dinv[p1.x] * __int_as_float(p1.y) * dic * s[p1.x];
    }
    if (k < c) {
        int2 p0 = csr[o + k];
        a += dinv[p0.x] * __int_as_float(p0.y) * dic * s[p0.x];
    }
    out[v] = 1.f / (1.f + expf(-(a + w2l[D])));
}

extern "C" void kernel_launch(void* const* d_in, const int* in_sizes, int n_in,
                              void* d_out, int out_size, void* d_ws, size_t ws_size,
                              hipStream_t stream) {
    const int* x          = (const int*)d_in[0];
    const int* edge_index = (const int*)d_in[1];
    const int* edge_attr  = (const int*)d_in[2];
    const float* atom_table = (const float*)d_in[3];
    const float* bond_table = (const float*)d_in[4];
    const float* W1 = (const float*)d_in[5];
    const float* b1 = (const float*)d_in[6];
    const float* W2 = (const float*)d_in[7];
    const float* b2 = (const float*)d_in[8];
    const float* lin_W = (const float*)d_in[9];
    const float* lin_b = (const float*)d_in[10];
    float* out = (float*)d_out;

    const int N = in_sizes[0] / 9;
    const int E = in_sizes[1] / 2;
    const int* row = edge_index;      // sources
    const int* col = edge_index + E;  // destinations

    float* ws = (float*)d_ws;
    float* ew    = ws;                          // E
    float* dinv  = ew + E;                      // N
    int*   cnt   = (int*)(dinv + N);            // N
    int*   off   = cnt + N;                     // N
    int*   rank  = off + N;                     // E
    int*   bsums = rank + E;                    // 512
    int2*  csr   = (int2*)(bsums + 512);        // E int2
    float* w2l   = (float*)(csr + E);           // 132
    float* sbuf  = w2l + 132;                   // N
    unsigned short* W1t = (unsigned short*)(sbuf + N);   // 16384
    unsigned short* hA  = W1t + 16384;                   // N*D bf16
    unsigned short* hB  = hA + (long)N * D;              // N*D bf16

    const int nb = (N + SCAN_B - 1) / SCAN_B;
    const int egrid = (E + 255) / 256;
    const int ngrid = (N + 255) / 256;

    // graph prep
    hipMemsetAsync(cnt, 0, (size_t)N * sizeof(int), stream);
    k_edge_w<<<egrid, 256, 0, stream>>>(edge_attr, bond_table, col, ew, rank, cnt, E);
    k_scan1<<<nb, SCAN_B, 0, stream>>>(cnt, off, bsums, N);
    k_scan2<<<1, 512, 0, stream>>>(bsums, nb);
    k_scan3<<<nb, SCAN_B, 0, stream>>>(off, bsums, N);
    k_fill<<<egrid, 256, 0, stream>>>(row, col, rank, off, ew, csr, E);
    k_degdinv<<<ngrid, 256, 0, stream>>>(csr, off, cnt, dinv, N);

    // weight prep
    k_wt<<<64, 256, 0, stream>>>(W1, W1t);
    k_fuse<<<1, 128, 0, stream>>>(W2, b2, lin_W, lin_b, w2l);

    // pipeline: atom -> hA; gather1 hA -> hB; mm1(+proj) hB -> sbuf; gather2s sbuf -> out
    k_atom<<<(N + 7) / 8, 256, 0, stream>>>(x, atom_table, hA, N);
    k_gather1<<<(N + 3) / 4, 256, 0, stream>>>(hA, off, cnt, csr, dinv, hB, N);
    k_mm1<<<(N + 127) / 128, 256, 0, stream>>>(hB, W1t, b1, w2l, sbuf, N);
    k_gather2s<<<ngrid, 256, 0, stream>>>(sbuf, off, cnt, csr, dinv, w2l, out, N);
}

// Round 6
// 159.095 us; speedup vs baseline: 14.0675x; 1.0307x over previous
//
#include <hip/hip_runtime.h>
#include <hip/hip_fp16.h>

#define D 128
typedef __attribute__((ext_vector_type(8))) short short8v;
typedef __attribute__((ext_vector_type(4))) float f32x4;

// ---- bf16 helpers ----
__device__ __forceinline__ float bf2f(unsigned short u) {
    union { unsigned int i; float f; } v; v.i = ((unsigned int)u) << 16; return v.f;
}
__device__ __forceinline__ unsigned short f2bf(float f) {
    union { float f; unsigned int i; } v; v.f = f;
    unsigned int r = v.i + 0x7FFF + ((v.i >> 16) & 1);
    return (unsigned short)(r >> 16);
}

// ---- fp8 e4m3fn encode, exact RNE (used 12.8M times, cold-ish path) ----
__device__ __forceinline__ unsigned int f8e(float f) {
    unsigned int u = __float_as_uint(f);
    unsigned int s = (u >> 24) & 0x80u;
    float a = fabsf(f);
    if (a < 0.015625f) {                        // e4m3 subnormal range
        int m = __float2int_rn(a * 512.0f);     // 0..8 (8 == min normal, seamless)
        return s | (unsigned int)m;
    }
    a = fminf(a, 448.0f);
    u = __float_as_uint(a);
    unsigned int r = u + 0x7FFFFu + ((u >> 20) & 1u);  // RNE to 3 mantissa bits
    return s | ((r >> 20) - 960u);              // exp rebias 127->7 packed with mantissa
}

// ---- fp8 decode via f16 embedding: returns value/256 (fold x256 into weight) ----
// f16 denormals are IEEE in HW on gfx9+, so e4m3 subnormals decode exactly.
__device__ __forceinline__ float f8d(unsigned int b) {
    union { unsigned short u; __half h; } c;
    c.u = (unsigned short)(((b & 0x80u) << 8) | ((b & 0x7fu) << 7));
    return __half2float(c.h);
}
__device__ __forceinline__ float4 dec4(unsigned int u) {
    float4 r;
    r.x = f8d(u & 0xffu);
    r.y = f8d((u >> 8) & 0xffu);
    r.z = f8d((u >> 16) & 0xffu);
    r.w = f8d(u >> 24);
    return r;
}

// ---------------- edge pass: weight + padded-bin histogram rank ----------------
// cnt_p bins padded to 64B lines: 600k atomics over 100k distinct lines, no line contention
__global__ void k_edge_w(const int* __restrict__ ea, const float* __restrict__ bt,
                         const int* __restrict__ col, float* __restrict__ ew,
                         int* __restrict__ rank, int* __restrict__ cntp, int E) {
    int e = blockIdx.x * blockDim.x + threadIdx.x;
    if (e >= E) return;
    float w = bt[ea[3 * e + 0]] + bt[16 + ea[3 * e + 1]] + bt[32 + ea[3 * e + 2]];
    ew[e] = w;
    rank[e] = atomicAdd(&cntp[col[e] << 4], 1);
}

// ---------------- exclusive scan over padded bins ----------------
#define SCAN_B 256
__global__ void k_scan1(const int* __restrict__ cntp, int* __restrict__ off,
                        int* __restrict__ bsums, int n) {
    __shared__ int s[SCAN_B];
    int tid = threadIdx.x;
    int i = blockIdx.x * SCAN_B + tid;
    int v = (i < n) ? cntp[i << 4] : 0;
    s[tid] = v;
    __syncthreads();
    for (int o = 1; o < SCAN_B; o <<= 1) {
        int t = (tid >= o) ? s[tid - o] : 0;
        __syncthreads();
        s[tid] += t;
        __syncthreads();
    }
    if (i < n) off[i] = s[tid] - v;
    if (tid == SCAN_B - 1) bsums[blockIdx.x] = s[tid];
}

__global__ void k_scan2(int* __restrict__ bsums, int nb) {
    __shared__ int s[512];
    int tid = threadIdx.x;
    int v = (tid < nb) ? bsums[tid] : 0;
    s[tid] = v;
    __syncthreads();
    for (int o = 1; o < 512; o <<= 1) {
        int t = (tid >= o) ? s[tid - o] : 0;
        __syncthreads();
        s[tid] += t;
        __syncthreads();
    }
    if (tid < nb) bsums[tid] = s[tid] - v;
}

__global__ void k_scan3(int* __restrict__ off, const int* __restrict__ bsums, int n, int E) {
    int i = blockIdx.x * SCAN_B + threadIdx.x;
    if (i < n) off[i] += bsums[blockIdx.x];
    if (blockIdx.x == 0 && threadIdx.x == 0) off[n] = E;  // sentinel
}

// ---------------- CSR fill (no atomics): slot = off[col] + rank ----------------
__global__ void k_fill(const int* __restrict__ row, const int* __restrict__ col,
                       const int* __restrict__ rank, const int* __restrict__ off,
                       const float* __restrict__ ew, int2* __restrict__ csr, int E) {
    int e = blockIdx.x * blockDim.x + threadIdx.x;
    if (e >= E) return;
    int p = off[col[e]] + rank[e];
    int2 v;
    v.x = row[e];
    v.y = __float_as_int(ew[e]);
    csr[p] = v;
}

// ---------------- degree from CSR segments -> dinv ----------------
__global__ void k_degdinv(const int2* __restrict__ csr, const int* __restrict__ off,
                          float* __restrict__ dinv, int n) {
    int i = blockIdx.x * blockDim.x + threadIdx.x;
    if (i >= n) return;
    int o = off[i], oe = off[i + 1];
    float d = 1.0f;  // self loop
    for (int k = o; k < oe; ++k) d += __int_as_float(csr[k].y);
    dinv[i] = d > 0.f ? rsqrtf(d) : 0.f;
}

// ---------------- fold dinv[row] into csr weight ----------------
__global__ void k_wscale(int2* __restrict__ csr, const float* __restrict__ dinv, int E) {
    int e = blockIdx.x * blockDim.x + threadIdx.x;
    if (e >= E) return;
    int2 p = csr[e];
    p.y = __float_as_int(__int_as_float(p.y) * dinv[p.x]);
    csr[e] = p;
}

// ---------------- W1 transpose + bf16 cvt: Wt[n][k] = W[k][n] ----------------
__global__ void k_wt(const float* __restrict__ W, unsigned short* __restrict__ Wt) {
    int idx = blockIdx.x * 256 + threadIdx.x;  // 16384
    int nn = idx >> 7, kk = idx & 127;
    Wt[idx] = f2bf(W[kk * D + nn]);
}

// ---------------- fold W2 @ lin_W -> w2l[128], w2l[128]=b2.lin+lin_b ----------------
__global__ void k_fuse(const float* __restrict__ W2, const float* __restrict__ b2,
                       const float* __restrict__ linW, const float* __restrict__ linb,
                       float* __restrict__ w2l) {
    int k = threadIdx.x;  // 128 threads
    float s = 0.f;
    for (int nn = 0; nn < D; ++nn) s += W2[k * D + nn] * linW[nn];
    w2l[k] = s;
    if (k == 0) {
        float cc = linb[0];
        for (int nn = 0; nn < D; ++nn) cc += b2[nn] * linW[nn];
        w2l[D] = cc;
    }
}

// ---------------- atom encoder -> fp8 (N x 32 uints) ----------------
__global__ void k_atom(const int* __restrict__ x, const float* __restrict__ at,
                       unsigned int* __restrict__ h8, int n) {
    int node = blockIdx.x * 8 + (threadIdx.x >> 5);
    int q = threadIdx.x & 31;  // 4 dims per thread
    if (node >= n) return;
    const int* xr = x + node * 9;
    float sx = 0.f, sy = 0.f, sz = 0.f, sw = 0.f;
#pragma unroll
    for (int f = 0; f < 9; ++f) {
        float4 v = *(const float4*)(at + (long)(xr[f] + f * 64) * D + q * 4);
        sx += v.x; sy += v.y; sz += v.z; sw += v.w;
    }
    unsigned int p = f8e(sx) | (f8e(sy) << 8) | (f8e(sz) << 16) | (f8e(sw) << 24);
    h8[(long)node * 32 + q] = p;
}

// ---------------- gather1: fp8 in, bf16 out; 32 lanes per node (2 nodes/wave) ----------------
__global__ void k_gather1(const unsigned int* __restrict__ h8, const int* __restrict__ off,
                          const int2* __restrict__ csr, const float* __restrict__ dinv,
                          unsigned short* __restrict__ outh, int n) {
    int node = blockIdx.x * 8 + (threadIdx.x >> 5);
    int q = threadIdx.x & 31;  // uint index: dims [4q, 4q+4)
    if (node >= n) return;
    int o = off[node], oe = off[node + 1];
    float dic = dinv[node];
    float w256 = dic * 256.0f;
    // self term
    float4 sf = dec4(h8[(long)node * 32 + q]);
    float ws = dic * w256;  // dic^2 * 256
    float ax = sf.x * ws, ay = sf.y * ws, az = sf.z * ws, aw = sf.w * ws;
    int k = o;
    for (; k + 2 <= oe; k += 2) {
        int2 p0 = csr[k], p1 = csr[k + 1];
        float w0 = __int_as_float(p0.y) * w256;  // dinv[r]*ew prefolded
        float w1 = __int_as_float(p1.y) * w256;
        unsigned int u0 = h8[(long)p0.x * 32 + q];
        unsigned int u1 = h8[(long)p1.x * 32 + q];
        float4 f0 = dec4(u0), f1 = dec4(u1);
        ax += f0.x * w0 + f1.x * w1;
        ay += f0.y * w0 + f1.y * w1;
        az += f0.z * w0 + f1.z * w1;
        aw += f0.w * w0 + f1.w * w1;
    }
    if (k < oe) {
        int2 p0 = csr[k];
        float w0 = __int_as_float(p0.y) * w256;
        float4 f0 = dec4(h8[(long)p0.x * 32 + q]);
        ax += f0.x * w0;
        ay += f0.y * w0;
        az += f0.z * w0;
        aw += f0.w * w0;
    }
    ushort4 ov;
    ov.x = f2bf(ax); ov.y = f2bf(ay); ov.z = f2bf(az); ov.w = f2bf(aw);
    *(ushort4*)(outh + (long)node * D + q * 4) = ov;
}

// ---------------- MFMA matmul + fused scalar projection ----------------
// s[r] = relu(A@W1 + b1)[r] . w2l   -- h1 never materialized
__global__ __launch_bounds__(256) void k_mm1(const unsigned short* __restrict__ A,
                                             const unsigned short* __restrict__ Wt,
                                             const float* __restrict__ bias,
                                             const float* __restrict__ w2l,
                                             float* __restrict__ sOut, int n) {
    const int tid = threadIdx.x;
    const int w = tid >> 6, l = tid & 63;
    const int lm = l & 15, lk = l >> 4;
    const long rbase = (long)blockIdx.x * 128 + w * 32;
    f32x4 acc[2][8] = {};
#pragma unroll
    for (int kc = 0; kc < 4; ++kc) {
        short8v bfr[8];
#pragma unroll
        for (int ct = 0; ct < 8; ++ct)
            bfr[ct] = *(const short8v*)(Wt + (long)(ct * 16 + lm) * D + kc * 32 + lk * 8);
#pragma unroll
        for (int rt = 0; rt < 2; ++rt) {
            long r = rbase + rt * 16 + lm;
            if (r >= n) r = n - 1;
            short8v afr = *(const short8v*)(A + r * D + kc * 32 + lk * 8);
#pragma unroll
            for (int ct = 0; ct < 8; ++ct)
                acc[rt][ct] = __builtin_amdgcn_mfma_f32_16x16x32_bf16(afr, bfr[ct], acc[rt][ct], 0, 0, 0);
        }
    }
    float bcol[8], wcol[8];
#pragma unroll
    for (int ct = 0; ct < 8; ++ct) {
        bcol[ct] = bias[ct * 16 + lm];
        wcol[ct] = w2l[ct * 16 + lm];
    }
    float p[2][4] = {};
#pragma unroll
    for (int rt = 0; rt < 2; ++rt)
#pragma unroll
        for (int ct = 0; ct < 8; ++ct)
#pragma unroll
            for (int j = 0; j < 4; ++j)
                p[rt][j] += fmaxf(acc[rt][ct][j] + bcol[ct], 0.f) * wcol[ct];
#pragma unroll
    for (int m = 1; m < 16; m <<= 1) {
#pragma unroll
        for (int rt = 0; rt < 2; ++rt)
#pragma unroll
            for (int j = 0; j < 4; ++j)
                p[rt][j] += __shfl_xor(p[rt][j], m);
    }
    if (lm == 0) {
#pragma unroll
        for (int rt = 0; rt < 2; ++rt)
#pragma unroll
            for (int j = 0; j < 4; ++j) {
                long r = rbase + rt * 16 + lk * 4 + j;
                if (r < n) sOut[r] = p[rt][j];
            }
    }
}

// ---------------- gather2 scalar: out[v] = sigmoid(dic^2 s[v] + sum w*s[r] + c) ----------------
__global__ void k_gather2s(const float* __restrict__ s, const int* __restrict__ off,
                           const int2* __restrict__ csr, const float* __restrict__ dinv,
                           const float* __restrict__ w2l, float* __restrict__ out, int n) {
    int v = blockIdx.x * blockDim.x + threadIdx.x;
    if (v >= n) return;
    int o = off[v], oe = off[v + 1];
    float dic = dinv[v];
    float a = s[v] * dic * dic;
    int k = o;
    for (; k + 2 <= oe; k += 2) {
        int2 p0 = csr[k], p1 = csr[k + 1];
        a += __int_as_float(p0.y) * dic * s[p0.x];
        a += __int_as_float(p1.y) * dic * s[p1.x];
    }
    if (k < oe) {
        int2 p0 = csr[k];
        a += __int_as_float(p0.y) * dic * s[p0.x];
    }
    out[v] = 1.f / (1.f + expf(-(a + w2l[D])));
}

extern "C" void kernel_launch(void* const* d_in, const int* in_sizes, int n_in,
                              void* d_out, int out_size, void* d_ws, size_t ws_size,
                              hipStream_t stream) {
    const int* x          = (const int*)d_in[0];
    const int* edge_index = (const int*)d_in[1];
    const int* edge_attr  = (const int*)d_in[2];
    const float* atom_table = (const float*)d_in[3];
    const float* bond_table = (const float*)d_in[4];
    const float* W1 = (const float*)d_in[5];
    const float* b1 = (const float*)d_in[6];
    const float* W2 = (const float*)d_in[7];
    const float* b2 = (const float*)d_in[8];
    const float* lin_W = (const float*)d_in[9];
    const float* lin_b = (const float*)d_in[10];
    float* out = (float*)d_out;

    const int N = in_sizes[0] / 9;
    const int E = in_sizes[1] / 2;
    const int* row = edge_index;      // sources
    const int* col = edge_index + E;  // destinations

    // workspace layout (ints; csr 8B-aligned by even prefix)
    float* ws = (float*)d_ws;
    float* ew    = ws;                          // E
    float* dinv  = ew + E;                      // N
    int*   cntp  = (int*)(dinv + N);            // 16N (64B-padded bins)
    int*   off   = cntp + 16 * (long)N;         // N+2
    int*   rank  = off + N + 2;                 // E
    int*   bsums = rank + E;                    // 512
    int2*  csr   = (int2*)(bsums + 512);        // E int2
    float* w2l   = (float*)(csr + E);           // 132
    float* sbuf  = w2l + 132;                   // N
    unsigned short* W1t = (unsigned short*)(sbuf + N);   // 16384 shorts
    unsigned int*   h8  = (unsigned int*)(W1t + 16384);  // N*32 uints (fp8 features)
    unsigned short* hB  = (unsigned short*)(h8 + 32 * (long)N);  // N*D bf16

    const int nb = (N + SCAN_B - 1) / SCAN_B;
    const int egrid = (E + 255) / 256;
    const int ngrid = (N + 255) / 256;

    // graph prep
    hipMemsetAsync(cntp, 0, (size_t)N * 16 * sizeof(int), stream);
    k_edge_w<<<egrid, 256, 0, stream>>>(edge_attr, bond_table, col, ew, rank, cntp, E);
    k_scan1<<<nb, SCAN_B, 0, stream>>>(cntp, off, bsums, N);
    k_scan2<<<1, 512, 0, stream>>>(bsums, nb);
    k_scan3<<<nb, SCAN_B, 0, stream>>>(off, bsums, N, E);
    k_fill<<<egrid, 256, 0, stream>>>(row, col, rank, off, ew, csr, E);
    k_degdinv<<<ngrid, 256, 0, stream>>>(csr, off, dinv, N);
    k_wscale<<<egrid, 256, 0, stream>>>(csr, dinv, E);

    // weight prep
    k_wt<<<64, 256, 0, stream>>>(W1, W1t);
    k_fuse<<<1, 128, 0, stream>>>(W2, b2, lin_W, lin_b, w2l);

    // pipeline: atom -> h8(fp8); gather1 h8 -> hB(bf16); mm1(+proj) hB -> sbuf; gather2s -> out
    k_atom<<<(N + 7) / 8, 256, 0, stream>>>(x, atom_table, h8, N);
    k_gather1<<<(N + 7) / 8, 256, 0, stream>>>(h8, off, csr, dinv, hB, N);
    k_mm1<<<(N + 127) / 128, 256, 0, stream>>>(hB, W1t, b1, w2l, sbuf, N);
    k_gather2s<<<ngrid, 256, 0, stream>>>(sbuf, off, csr, dinv, w2l, out, N);
}

// Round 7
// 154.163 us; speedup vs baseline: 14.5176x; 1.0320x over previous
//
#include <hip/hip_runtime.h>
#include <hip/hip_fp16.h>

#define D 128
typedef __attribute__((ext_vector_type(8))) short short8v;
typedef __attribute__((ext_vector_type(4))) float f32x4;

// ---- bf16 helpers ----
__device__ __forceinline__ float bf2f(unsigned short u) {
    union { unsigned int i; float f; } v; v.i = ((unsigned int)u) << 16; return v.f;
}
__device__ __forceinline__ unsigned short f2bf(float f) {
    union { float f; unsigned int i; } v; v.f = f;
    unsigned int r = v.i + 0x7FFF + ((v.i >> 16) & 1);
    return (unsigned short)(r >> 16);
}

// ---- fp8 e4m3fn encode, exact RNE ----
__device__ __forceinline__ unsigned int f8e(float f) {
    unsigned int u = __float_as_uint(f);
    unsigned int s = (u >> 24) & 0x80u;
    float a = fabsf(f);
    if (a < 0.015625f) {
        int m = __float2int_rn(a * 512.0f);
        return s | (unsigned int)m;
    }
    a = fminf(a, 448.0f);
    u = __float_as_uint(a);
    unsigned int r = u + 0x7FFFFu + ((u >> 20) & 1u);
    return s | ((r >> 20) - 960u);
}

// ---- fp8 decode via f16 embedding: returns value/256 (x256 folded into weight) ----
__device__ __forceinline__ float f8d(unsigned int b) {
    union { unsigned short u; __half h; } c;
    c.u = (unsigned short)(((b & 0x80u) << 8) | ((b & 0x7fu) << 7));
    return __half2float(c.h);
}
__device__ __forceinline__ float4 dec4(unsigned int u) {
    float4 r;
    r.x = f8d(u & 0xffu);
    r.y = f8d((u >> 8) & 0xffu);
    r.z = f8d((u >> 16) & 0xffu);
    r.w = f8d(u >> 24);
    return r;
}

// ---------------- fast zero (replaces rocclr fillBuffer: 42us -> ~2us) ----------------
__global__ void k_zero(int4* __restrict__ p, int n4) {
    int stride = gridDim.x * blockDim.x;
    for (int i = blockIdx.x * blockDim.x + threadIdx.x; i < n4; i += stride)
        p[i] = make_int4(0, 0, 0, 0);
}

// ---------------- edge pass: weight + padded-bin histogram rank ----------------
__global__ void k_edge_w(const int* __restrict__ ea, const float* __restrict__ bt,
                         const int* __restrict__ col, float* __restrict__ ew,
                         int* __restrict__ rank, int* __restrict__ cntp, int E) {
    int e = blockIdx.x * blockDim.x + threadIdx.x;
    if (e >= E) return;
    float w = bt[ea[3 * e + 0]] + bt[16 + ea[3 * e + 1]] + bt[32 + ea[3 * e + 2]];
    ew[e] = w;
    rank[e] = atomicAdd(&cntp[col[e] << 4], 1);
}

// ---------------- exclusive scan over padded bins ----------------
#define SCAN_B 256
__global__ void k_scan1(const int* __restrict__ cntp, int* __restrict__ off,
                        int* __restrict__ bsums, int n) {
    __shared__ int s[SCAN_B];
    int tid = threadIdx.x;
    int i = blockIdx.x * SCAN_B + tid;
    int v = (i < n) ? cntp[i << 4] : 0;
    s[tid] = v;
    __syncthreads();
    for (int o = 1; o < SCAN_B; o <<= 1) {
        int t = (tid >= o) ? s[tid - o] : 0;
        __syncthreads();
        s[tid] += t;
        __syncthreads();
    }
    if (i < n) off[i] = s[tid] - v;
    if (tid == SCAN_B - 1) bsums[blockIdx.x] = s[tid];
}

__global__ void k_scan2(int* __restrict__ bsums, int nb) {
    __shared__ int s[512];
    int tid = threadIdx.x;
    int v = (tid < nb) ? bsums[tid] : 0;
    s[tid] = v;
    __syncthreads();
    for (int o = 1; o < 512; o <<= 1) {
        int t = (tid >= o) ? s[tid - o] : 0;
        __syncthreads();
        s[tid] += t;
        __syncthreads();
    }
    if (tid < nb) bsums[tid] = s[tid] - v;
}

__global__ void k_scan3(int* __restrict__ off, const int* __restrict__ bsums, int n, int E) {
    int i = blockIdx.x * SCAN_B + threadIdx.x;
    if (i < n) off[i] += bsums[blockIdx.x];
    if (blockIdx.x == 0 && threadIdx.x == 0) off[n] = E;  // sentinel
}

// ---------------- CSR fill (no atomics) ----------------
__global__ void k_fill(const int* __restrict__ row, const int* __restrict__ col,
                       const int* __restrict__ rank, const int* __restrict__ off,
                       const float* __restrict__ ew, int2* __restrict__ csr, int E) {
    int e = blockIdx.x * blockDim.x + threadIdx.x;
    if (e >= E) return;
    int p = off[col[e]] + rank[e];
    int2 v;
    v.x = row[e];
    v.y = __float_as_int(ew[e]);
    csr[p] = v;
}

// ---------------- degree from CSR segments -> dinv ----------------
__global__ void k_degdinv(const int2* __restrict__ csr, const int* __restrict__ off,
                          float* __restrict__ dinv, int n) {
    int i = blockIdx.x * blockDim.x + threadIdx.x;
    if (i >= n) return;
    int o = off[i], oe = off[i + 1];
    float d = 1.0f;  // self loop
    for (int k = o; k < oe; ++k) d += __int_as_float(csr[k].y);
    dinv[i] = d > 0.f ? rsqrtf(d) : 0.f;
}

// ---------------- fold dinv[row] into csr weight ----------------
__global__ void k_wscale(int2* __restrict__ csr, const float* __restrict__ dinv, int E) {
    int e = blockIdx.x * blockDim.x + threadIdx.x;
    if (e >= E) return;
    int2 p = csr[e];
    p.y = __float_as_int(__int_as_float(p.y) * dinv[p.x]);
    csr[e] = p;
}

// ---------------- merged weight prep: blocks 0..63 transpose W1; block 64 folds W2@linW ----------------
__global__ void k_wprep(const float* __restrict__ W1, unsigned short* __restrict__ Wt,
                        const float* __restrict__ W2, const float* __restrict__ b2,
                        const float* __restrict__ linW, const float* __restrict__ linb,
                        float* __restrict__ w2l) {
    if (blockIdx.x < 64) {
        int idx = blockIdx.x * 256 + threadIdx.x;  // 16384
        int nn = idx >> 7, kk = idx & 127;
        Wt[idx] = f2bf(W1[kk * D + nn]);
    } else if (threadIdx.x < 128) {
        int k = threadIdx.x;
        float s = 0.f;
        for (int nn = 0; nn < D; ++nn) s += W2[k * D + nn] * linW[nn];
        w2l[k] = s;
        if (k == 0) {
            float cc = linb[0];
            for (int nn = 0; nn < D; ++nn) cc += b2[nn] * linW[nn];
            w2l[D] = cc;
        }
    }
}

// ---------------- atom encoder -> fp8 (N x 32 uints) ----------------
__global__ void k_atom(const int* __restrict__ x, const float* __restrict__ at,
                       unsigned int* __restrict__ h8, int n) {
    int node = blockIdx.x * 8 + (threadIdx.x >> 5);
    int q = threadIdx.x & 31;
    if (node >= n) return;
    const int* xr = x + node * 9;
    float sx = 0.f, sy = 0.f, sz = 0.f, sw = 0.f;
#pragma unroll
    for (int f = 0; f < 9; ++f) {
        float4 v = *(const float4*)(at + (long)(xr[f] + f * 64) * D + q * 4);
        sx += v.x; sy += v.y; sz += v.z; sw += v.w;
    }
    unsigned int p = f8e(sx) | (f8e(sy) << 8) | (f8e(sz) << 16) | (f8e(sw) << 24);
    h8[(long)node * 32 + q] = p;
}

// ---------------- gather1: fp8 in, bf16 out; 32 lanes/node; unroll-4 ----------------
__global__ void k_gather1(const unsigned int* __restrict__ h8, const int* __restrict__ off,
                          const int2* __restrict__ csr, const float* __restrict__ dinv,
                          unsigned short* __restrict__ outh, int n) {
    int node = blockIdx.x * 8 + (threadIdx.x >> 5);
    int q = threadIdx.x & 31;
    if (node >= n) return;
    int o = off[node], oe = off[node + 1];
    float dic = dinv[node];
    float w256 = dic * 256.0f;
    float4 sf = dec4(h8[(long)node * 32 + q]);
    float wsx = dic * w256;
    float ax0 = sf.x * wsx, ay0 = sf.y * wsx, az0 = sf.z * wsx, aw0 = sf.w * wsx;
    float ax1 = 0.f, ay1 = 0.f, az1 = 0.f, aw1 = 0.f;
    int k = o;
    for (; k + 4 <= oe; k += 4) {
        int2 p0 = csr[k], p1 = csr[k + 1], p2 = csr[k + 2], p3 = csr[k + 3];
        unsigned int u0 = h8[(long)p0.x * 32 + q];
        unsigned int u1 = h8[(long)p1.x * 32 + q];
        unsigned int u2 = h8[(long)p2.x * 32 + q];
        unsigned int u3 = h8[(long)p3.x * 32 + q];
        float w0 = __int_as_float(p0.y) * w256;
        float w1 = __int_as_float(p1.y) * w256;
        float w2 = __int_as_float(p2.y) * w256;
        float w3 = __int_as_float(p3.y) * w256;
        float4 f0 = dec4(u0), f1 = dec4(u1), f2 = dec4(u2), f3 = dec4(u3);
        ax0 += f0.x * w0 + f1.x * w1; ax1 += f2.x * w2 + f3.x * w3;
        ay0 += f0.y * w0 + f1.y * w1; ay1 += f2.y * w2 + f3.y * w3;
        az0 += f0.z * w0 + f1.z * w1; az1 += f2.z * w2 + f3.z * w3;
        aw0 += f0.w * w0 + f1.w * w1; aw1 += f2.w * w2 + f3.w * w3;
    }
    for (; k < oe; ++k) {
        int2 p0 = csr[k];
        float w0 = __int_as_float(p0.y) * w256;
        float4 f0 = dec4(h8[(long)p0.x * 32 + q]);
        ax0 += f0.x * w0;
        ay0 += f0.y * w0;
        az0 += f0.z * w0;
        aw0 += f0.w * w0;
    }
    ushort4 ov;
    ov.x = f2bf(ax0 + ax1); ov.y = f2bf(ay0 + ay1);
    ov.z = f2bf(az0 + az1); ov.w = f2bf(aw0 + aw1);
    *(ushort4*)(outh + (long)node * D + q * 4) = ov;
}

// ---------------- MFMA matmul + fused scalar projection ----------------
__global__ __launch_bounds__(256) void k_mm1(const unsigned short* __restrict__ A,
                                             const unsigned short* __restrict__ Wt,
                                             const float* __restrict__ bias,
                                             const float* __restrict__ w2l,
                                             float* __restrict__ sOut, int n) {
    const int tid = threadIdx.x;
    const int w = tid >> 6, l = tid & 63;
    const int lm = l & 15, lk = l >> 4;
    const long rbase = (long)blockIdx.x * 128 + w * 32;
    f32x4 acc[2][8] = {};
#pragma unroll
    for (int kc = 0; kc < 4; ++kc) {
        short8v bfr[8];
#pragma unroll
        for (int ct = 0; ct < 8; ++ct)
            bfr[ct] = *(const short8v*)(Wt + (long)(ct * 16 + lm) * D + kc * 32 + lk * 8);
#pragma unroll
        for (int rt = 0; rt < 2; ++rt) {
            long r = rbase + rt * 16 + lm;
            if (r >= n) r = n - 1;
            short8v afr = *(const short8v*)(A + r * D + kc * 32 + lk * 8);
#pragma unroll
            for (int ct = 0; ct < 8; ++ct)
                acc[rt][ct] = __builtin_amdgcn_mfma_f32_16x16x32_bf16(afr, bfr[ct], acc[rt][ct], 0, 0, 0);
        }
    }
    float bcol[8], wcol[8];
#pragma unroll
    for (int ct = 0; ct < 8; ++ct) {
        bcol[ct] = bias[ct * 16 + lm];
        wcol[ct] = w2l[ct * 16 + lm];
    }
    float p[2][4] = {};
#pragma unroll
    for (int rt = 0; rt < 2; ++rt)
#pragma unroll
        for (int ct = 0; ct < 8; ++ct)
#pragma unroll
            for (int j = 0; j < 4; ++j)
                p[rt][j] += fmaxf(acc[rt][ct][j] + bcol[ct], 0.f) * wcol[ct];
#pragma unroll
    for (int m = 1; m < 16; m <<= 1) {
#pragma unroll
        for (int rt = 0; rt < 2; ++rt)
#pragma unroll
            for (int j = 0; j < 4; ++j)
                p[rt][j] += __shfl_xor(p[rt][j], m);
    }
    if (lm == 0) {
#pragma unroll
        for (int rt = 0; rt < 2; ++rt)
#pragma unroll
            for (int j = 0; j < 4; ++j) {
                long r = rbase + rt * 16 + lk * 4 + j;
                if (r < n) sOut[r] = p[rt][j];
            }
    }
}

// ---------------- gather2 scalar ----------------
__global__ void k_gather2s(const float* __restrict__ s, const int* __restrict__ off,
                           const int2* __restrict__ csr, const float* __restrict__ dinv,
                           const float* __restrict__ w2l, float* __restrict__ out, int n) {
    int v = blockIdx.x * blockDim.x + threadIdx.x;
    if (v >= n) return;
    int o = off[v], oe = off[v + 1];
    float dic = dinv[v];
    float a = s[v] * dic * dic;
    int k = o;
    for (; k + 2 <= oe; k += 2) {
        int2 p0 = csr[k], p1 = csr[k + 1];
        a += __int_as_float(p0.y) * dic * s[p0.x];
        a += __int_as_float(p1.y) * dic * s[p1.x];
    }
    if (k < oe) {
        int2 p0 = csr[k];
        a += __int_as_float(p0.y) * dic * s[p0.x];
    }
    out[v] = 1.f / (1.f + expf(-(a + w2l[D])));
}

extern "C" void kernel_launch(void* const* d_in, const int* in_sizes, int n_in,
                              void* d_out, int out_size, void* d_ws, size_t ws_size,
                              hipStream_t stream) {
    const int* x          = (const int*)d_in[0];
    const int* edge_index = (const int*)d_in[1];
    const int* edge_attr  = (const int*)d_in[2];
    const float* atom_table = (const float*)d_in[3];
    const float* bond_table = (const float*)d_in[4];
    const float* W1 = (const float*)d_in[5];
    const float* b1 = (const float*)d_in[6];
    const float* W2 = (const float*)d_in[7];
    const float* b2 = (const float*)d_in[8];
    const float* lin_W = (const float*)d_in[9];
    const float* lin_b = (const float*)d_in[10];
    float* out = (float*)d_out;

    const int N = in_sizes[0] / 9;
    const int E = in_sizes[1] / 2;
    const int* row = edge_index;
    const int* col = edge_index + E;

    float* ws = (float*)d_ws;
    float* ew    = ws;                          // E
    float* dinv  = ew + E;                      // N
    int*   cntp  = (int*)(dinv + N);            // 16N (64B-padded bins)
    int*   off   = cntp + 16 * (long)N;         // N+2
    int*   rank  = off + N + 2;                 // E
    int*   bsums = rank + E;                    // 512
    int2*  csr   = (int2*)(bsums + 512);        // E int2
    float* w2l   = (float*)(csr + E);           // 132
    float* sbuf  = w2l + 132;                   // N
    unsigned short* W1t = (unsigned short*)(sbuf + N);   // 16384
    unsigned int*   h8  = (unsigned int*)(W1t + 16384);  // N*32 uints
    unsigned short* hB  = (unsigned short*)(h8 + 32 * (long)N);  // N*D bf16

    const int nb = (N + SCAN_B - 1) / SCAN_B;
    const int egrid = (E + 255) / 256;
    const int ngrid = (N + 255) / 256;

    // graph prep
    k_zero<<<1024, 256, 0, stream>>>((int4*)cntp, 4 * N);
    k_edge_w<<<egrid, 256, 0, stream>>>(edge_attr, bond_table, col, ew, rank, cntp, E);
    k_scan1<<<nb, SCAN_B, 0, stream>>>(cntp, off, bsums, N);
    k_scan2<<<1, 512, 0, stream>>>(bsums, nb);
    k_scan3<<<nb, SCAN_B, 0, stream>>>(off, bsums, N, E);
    k_fill<<<egrid, 256, 0, stream>>>(row, col, rank, off, ew, csr, E);
    k_degdinv<<<ngrid, 256, 0, stream>>>(csr, off, dinv, N);
    k_wscale<<<egrid, 256, 0, stream>>>(csr, dinv, E);

    // weight prep (merged)
    k_wprep<<<65, 256, 0, stream>>>(W1, W1t, W2, b2, lin_W, lin_b, w2l);

    // pipeline
    k_atom<<<(N + 7) / 8, 256, 0, stream>>>(x, atom_table, h8, N);
    k_gather1<<<(N + 7) / 8, 256, 0, stream>>>(h8, off, csr, dinv, hB, N);
    k_mm1<<<(N + 127) / 128, 256, 0, stream>>>(hB, W1t, b1, w2l, sbuf, N);
    k_gather2s<<<ngrid, 256, 0, stream>>>(sbuf, off, csr, dinv, w2l, out, N);
}

// Round 8
// 146.578 us; speedup vs baseline: 15.2689x; 1.0518x over previous
//
#include <hip/hip_runtime.h>
#include <hip/hip_fp16.h>

#define D 128
typedef __attribute__((ext_vector_type(8))) short short8v;
typedef __attribute__((ext_vector_type(4))) float f32x4;

// ---- bf16 helpers ----
__device__ __forceinline__ float bf2f(unsigned short u) {
    union { unsigned int i; float f; } v; v.i = ((unsigned int)u) << 16; return v.f;
}
__device__ __forceinline__ unsigned short f2bf(float f) {
    union { float f; unsigned int i; } v; v.f = f;
    unsigned int r = v.i + 0x7FFF + ((v.i >> 16) & 1);
    return (unsigned short)(r >> 16);
}

// ---- fp8 e4m3fn encode, exact RNE ----
__device__ __forceinline__ unsigned int f8e(float f) {
    unsigned int u = __float_as_uint(f);
    unsigned int s = (u >> 24) & 0x80u;
    float a = fabsf(f);
    if (a < 0.015625f) {
        int m = __float2int_rn(a * 512.0f);
        return s | (unsigned int)m;
    }
    a = fminf(a, 448.0f);
    u = __float_as_uint(a);
    unsigned int r = u + 0x7FFFFu + ((u >> 20) & 1u);
    return s | ((r >> 20) - 960u);
}

// ---- fp8 decode via f16 embedding: returns value/256 (x256 folded at the end) ----
__device__ __forceinline__ float f8d(unsigned int b) {
    union { unsigned short u; __half h; } c;
    c.u = (unsigned short)(((b & 0x80u) << 8) | ((b & 0x7fu) << 7));
    return __half2float(c.h);
}
__device__ __forceinline__ float4 dec4(unsigned int u) {
    float4 r;
    r.x = f8d(u & 0xffu);
    r.y = f8d((u >> 8) & 0xffu);
    r.z = f8d((u >> 16) & 0xffu);
    r.w = f8d(u >> 24);
    return r;
}

// ---------------- k_pre: zero cntp | W1 transpose->bf16 | fold w2l | atom table->bf16 ----------------
__global__ void k_pre(int4* __restrict__ cntp4, int n4,
                      const float* __restrict__ W1, unsigned short* __restrict__ Wt,
                      const float* __restrict__ W2, const float* __restrict__ b2,
                      const float* __restrict__ linW, const float* __restrict__ linb,
                      float* __restrict__ w2l,
                      const float* __restrict__ at, unsigned short* __restrict__ at16) {
    int b = blockIdx.x, t = threadIdx.x;
    if (b < 256) {                       // zero padded histogram bins
        int stride = 256 * 256;
        for (int i = b * 256 + t; i < n4; i += stride)
            cntp4[i] = make_int4(0, 0, 0, 0);
    } else if (b < 320) {                // Wt[n][k] = bf16(W1[k][n])
        int idx = (b - 256) * 256 + t;   // 16384
        int nn = idx >> 7, kk = idx & 127;
        Wt[idx] = f2bf(W1[kk * D + nn]);
    } else if (b == 320) {               // w2l = W2 @ linW ; w2l[D] = b2.linW + lin_b
        if (t < 128) {
            float s = 0.f;
            for (int nn = 0; nn < D; ++nn) s += W2[t * D + nn] * linW[nn];
            w2l[t] = s;
            if (t == 0) {
                float cc = linb[0];
                for (int nn = 0; nn < D; ++nn) cc += b2[nn] * linW[nn];
                w2l[D] = cc;
            }
        }
    } else {                             // atom table fp32 -> bf16 (73728 elems = 18432 float4)
        int idx = (b - 321) * 256 + t;
        if (idx < 18432) {
            float4 v = ((const float4*)at)[idx];
            ushort4 o;
            o.x = f2bf(v.x); o.y = f2bf(v.y); o.z = f2bf(v.z); o.w = f2bf(v.w);
            ((ushort4*)at16)[idx] = o;
        }
    }
}

// ---------------- edge pass: weight + padded-bin histogram rank ----------------
__global__ void k_edge_w(const int* __restrict__ ea, const float* __restrict__ bt,
                         const int* __restrict__ col, float* __restrict__ ew,
                         int* __restrict__ rank, int* __restrict__ cntp, int E) {
    int e = blockIdx.x * blockDim.x + threadIdx.x;
    if (e >= E) return;
    float w = bt[ea[3 * e + 0]] + bt[16 + ea[3 * e + 1]] + bt[32 + ea[3 * e + 2]];
    ew[e] = w;
    rank[e] = atomicAdd(&cntp[col[e] << 4], 1);
}

// ---------------- exclusive scan over padded bins ----------------
#define SCAN_B 256
__global__ void k_scan1(const int* __restrict__ cntp, int* __restrict__ off,
                        int* __restrict__ bsums, int n) {
    __shared__ int s[SCAN_B];
    int tid = threadIdx.x;
    int i = blockIdx.x * SCAN_B + tid;
    int v = (i < n) ? cntp[i << 4] : 0;
    s[tid] = v;
    __syncthreads();
    for (int o = 1; o < SCAN_B; o <<= 1) {
        int t = (tid >= o) ? s[tid - o] : 0;
        __syncthreads();
        s[tid] += t;
        __syncthreads();
    }
    if (i < n) off[i] = s[tid] - v;
    if (tid == SCAN_B - 1) bsums[blockIdx.x] = s[tid];
}

__global__ void k_scan2(int* __restrict__ bsums, int nb) {
    __shared__ int s[512];
    int tid = threadIdx.x;
    int v = (tid < nb) ? bsums[tid] : 0;
    s[tid] = v;
    __syncthreads();
    for (int o = 1; o < 512; o <<= 1) {
        int t = (tid >= o) ? s[tid - o] : 0;
        __syncthreads();
        s[tid] += t;
        __syncthreads();
    }
    if (tid < nb) bsums[tid] = s[tid] - v;
}

__global__ void k_scan3(int* __restrict__ off, const int* __restrict__ bsums, int n, int E) {
    int i = blockIdx.x * SCAN_B + threadIdx.x;
    if (i < n) off[i] += bsums[blockIdx.x];
    if (blockIdx.x == 0 && threadIdx.x == 0) off[n] = E;  // sentinel
}

// ---------------- CSR fill (no atomics): csr = (row, ew) ----------------
__global__ void k_fill(const int* __restrict__ row, const int* __restrict__ col,
                       const int* __restrict__ rank, const int* __restrict__ off,
                       const float* __restrict__ ew, int2* __restrict__ csr, int E) {
    int e = blockIdx.x * blockDim.x + threadIdx.x;
    if (e >= E) return;
    int p = off[col[e]] + rank[e];
    int2 v;
    v.x = row[e];
    v.y = __float_as_int(ew[e]);
    csr[p] = v;
}

// ---------------- k_node: deg -> dinv -> g = dinv * AtomEnc(x)  (fp8) ----------------
// 32 lanes per node: segment-sum ew, rsqrt, then encode scaled features.
__global__ __launch_bounds__(256) void k_node(const int* __restrict__ x,
                                              const unsigned short* __restrict__ at16,
                                              const int* __restrict__ off,
                                              const int2* __restrict__ csr,
                                              float* __restrict__ dinv,
                                              unsigned int* __restrict__ h8, int n) {
    int node = blockIdx.x * 8 + (threadIdx.x >> 5);
    int q = threadIdx.x & 31;
    if (node >= n) return;
    int o = off[node], oe = off[node + 1];
    float d = 0.f;
    for (int k = o + q; k < oe; k += 32) d += __int_as_float(csr[k].y);
#pragma unroll
    for (int m = 1; m < 32; m <<= 1) d += __shfl_xor(d, m, 32);
    d += 1.0f;  // self loop
    float di = rsqrtf(d);
    if (q == 0) dinv[node] = di;
    const int* xr = x + node * 9;
    float sx = 0.f, sy = 0.f, sz = 0.f, sw = 0.f;
#pragma unroll
    for (int f = 0; f < 9; ++f) {
        ushort4 v = *(const ushort4*)(at16 + (long)(xr[f] + f * 64) * D + q * 4);
        sx += bf2f(v.x); sy += bf2f(v.y); sz += bf2f(v.z); sw += bf2f(v.w);
    }
    unsigned int p = f8e(sx * di) | (f8e(sy * di) << 8) | (f8e(sz * di) << 16) | (f8e(sw * di) << 24);
    h8[(long)node * 32 + q] = p;
}

// ---------------- gather1: out1[c] = dinv[c]*(g[c] + sum ew*g[r]), bf16 out ----------------
__global__ void k_gather1(const unsigned int* __restrict__ h8, const int* __restrict__ off,
                          const int2* __restrict__ csr, const float* __restrict__ dinv,
                          unsigned short* __restrict__ outh, int n) {
    int node = blockIdx.x * 8 + (threadIdx.x >> 5);
    int q = threadIdx.x & 31;
    if (node >= n) return;
    int o = off[node], oe = off[node + 1];
    float4 sf = dec4(h8[(long)node * 32 + q]);
    float ax0 = sf.x, ay0 = sf.y, az0 = sf.z, aw0 = sf.w;   // self term, weight 1
    float ax1 = 0.f, ay1 = 0.f, az1 = 0.f, aw1 = 0.f;
    int k = o;
    for (; k + 4 <= oe; k += 4) {
        int2 p0 = csr[k], p1 = csr[k + 1], p2 = csr[k + 2], p3 = csr[k + 3];
        unsigned int u0 = h8[(long)p0.x * 32 + q];
        unsigned int u1 = h8[(long)p1.x * 32 + q];
        unsigned int u2 = h8[(long)p2.x * 32 + q];
        unsigned int u3 = h8[(long)p3.x * 32 + q];
        float w0 = __int_as_float(p0.y), w1 = __int_as_float(p1.y);
        float w2 = __int_as_float(p2.y), w3 = __int_as_float(p3.y);
        float4 f0 = dec4(u0), f1 = dec4(u1), f2 = dec4(u2), f3 = dec4(u3);
        ax0 += f0.x * w0 + f1.x * w1; ax1 += f2.x * w2 + f3.x * w3;
        ay0 += f0.y * w0 + f1.y * w1; ay1 += f2.y * w2 + f3.y * w3;
        az0 += f0.z * w0 + f1.z * w1; az1 += f2.z * w2 + f3.z * w3;
        aw0 += f0.w * w0 + f1.w * w1; aw1 += f2.w * w2 + f3.w * w3;
    }
    for (; k < oe; ++k) {
        int2 p0 = csr[k];
        float w0 = __int_as_float(p0.y);
        float4 f0 = dec4(h8[(long)p0.x * 32 + q]);
        ax0 += f0.x * w0;
        ay0 += f0.y * w0;
        az0 += f0.z * w0;
        aw0 += f0.w * w0;
    }
    float s256 = dinv[node] * 256.0f;   // undo /256 decode + apply dinv[c]
    ushort4 ov;
    ov.x = f2bf((ax0 + ax1) * s256); ov.y = f2bf((ay0 + ay1) * s256);
    ov.z = f2bf((az0 + az1) * s256); ov.w = f2bf((aw0 + aw1) * s256);
    *(ushort4*)(outh + (long)node * D + q * 4) = ov;
}

// ---------------- MFMA matmul + fused scalar projection: t[r] = dinv[r]*(relu(A@W1+b1).w2l) ----------------
__global__ __launch_bounds__(256) void k_mm1(const unsigned short* __restrict__ A,
                                             const unsigned short* __restrict__ Wt,
                                             const float* __restrict__ bias,
                                             const float* __restrict__ w2l,
                                             const float* __restrict__ dinv,
                                             float* __restrict__ tOut, int n) {
    const int tid = threadIdx.x;
    const int w = tid >> 6, l = tid & 63;
    const int lm = l & 15, lk = l >> 4;
    const long rbase = (long)blockIdx.x * 128 + w * 32;
    f32x4 acc[2][8] = {};
#pragma unroll
    for (int kc = 0; kc < 4; ++kc) {
        short8v bfr[8];
#pragma unroll
        for (int ct = 0; ct < 8; ++ct)
            bfr[ct] = *(const short8v*)(Wt + (long)(ct * 16 + lm) * D + kc * 32 + lk * 8);
#pragma unroll
        for (int rt = 0; rt < 2; ++rt) {
            long r = rbase + rt * 16 + lm;
            if (r >= n) r = n - 1;
            short8v afr = *(const short8v*)(A + r * D + kc * 32 + lk * 8);
#pragma unroll
            for (int ct = 0; ct < 8; ++ct)
                acc[rt][ct] = __builtin_amdgcn_mfma_f32_16x16x32_bf16(afr, bfr[ct], acc[rt][ct], 0, 0, 0);
        }
    }
    float bcol[8], wcol[8];
#pragma unroll
    for (int ct = 0; ct < 8; ++ct) {
        bcol[ct] = bias[ct * 16 + lm];
        wcol[ct] = w2l[ct * 16 + lm];
    }
    float p[2][4] = {};
#pragma unroll
    for (int rt = 0; rt < 2; ++rt)
#pragma unroll
        for (int ct = 0; ct < 8; ++ct)
#pragma unroll
            for (int j = 0; j < 4; ++j)
                p[rt][j] += fmaxf(acc[rt][ct][j] + bcol[ct], 0.f) * wcol[ct];
#pragma unroll
    for (int m = 1; m < 16; m <<= 1) {
#pragma unroll
        for (int rt = 0; rt < 2; ++rt)
#pragma unroll
            for (int j = 0; j < 4; ++j)
                p[rt][j] += __shfl_xor(p[rt][j], m);
    }
    if (lm == 0) {
#pragma unroll
        for (int rt = 0; rt < 2; ++rt)
#pragma unroll
            for (int j = 0; j < 4; ++j) {
                long r = rbase + rt * 16 + lk * 4 + j;
                if (r < n) tOut[r] = p[rt][j] * dinv[r];
            }
    }
}

// ---------------- gather2 scalar: out[v] = sigmoid(dinv[v]*(t[v] + sum ew*t[r]) + c) ----------------
__global__ void k_gather2s(const float* __restrict__ t, const int* __restrict__ off,
                           const int2* __restrict__ csr, const float* __restrict__ dinv,
                           const float* __restrict__ w2l, float* __restrict__ out, int n) {
    int v = blockIdx.x * blockDim.x + threadIdx.x;
    if (v >= n) return;
    int o = off[v], oe = off[v + 1];
    float a = t[v];   // self term
    int k = o;
    for (; k + 2 <= oe; k += 2) {
        int2 p0 = csr[k], p1 = csr[k + 1];
        a += __int_as_float(p0.y) * t[p0.x];
        a += __int_as_float(p1.y) * t[p1.x];
    }
    if (k < oe) {
        int2 p0 = csr[k];
        a += __int_as_float(p0.y) * t[p0.x];
    }
    out[v] = 1.f / (1.f + expf(-(dinv[v] * a + w2l[D])));
}

extern "C" void kernel_launch(void* const* d_in, const int* in_sizes, int n_in,
                              void* d_out, int out_size, void* d_ws, size_t ws_size,
                              hipStream_t stream) {
    const int* x          = (const int*)d_in[0];
    const int* edge_index = (const int*)d_in[1];
    const int* edge_attr  = (const int*)d_in[2];
    const float* atom_table = (const float*)d_in[3];
    const float* bond_table = (const float*)d_in[4];
    const float* W1 = (const float*)d_in[5];
    const float* b1 = (const float*)d_in[6];
    const float* W2 = (const float*)d_in[7];
    const float* b2 = (const float*)d_in[8];
    const float* lin_W = (const float*)d_in[9];
    const float* lin_b = (const float*)d_in[10];
    float* out = (float*)d_out;

    const int N = in_sizes[0] / 9;
    const int E = in_sizes[1] / 2;
    const int* row = edge_index;
    const int* col = edge_index + E;

    float* ws = (float*)d_ws;
    float* ew    = ws;                          // E
    float* dinv  = ew + E;                      // N
    int*   cntp  = (int*)(dinv + N);            // 16N (64B-padded bins)
    int*   off   = cntp + 16 * (long)N;         // N+2
    int*   rank  = off + N + 2;                 // E
    int*   bsums = rank + E;                    // 512
    int2*  csr   = (int2*)(bsums + 512);        // E int2
    float* w2l   = (float*)(csr + E);           // 132
    float* tbuf  = w2l + 132;                   // N
    unsigned short* W1t  = (unsigned short*)(tbuf + N);   // 16384
    unsigned short* at16 = W1t + 16384;                   // 73728
    unsigned int*   h8   = (unsigned int*)(at16 + 73728); // N*32
    unsigned short* hB   = (unsigned short*)(h8 + 32 * (long)N);  // N*D bf16

    const int nb = (N + SCAN_B - 1) / SCAN_B;
    const int egrid = (E + 255) / 256;
    const int ngrid = (N + 255) / 256;

    // prep: zero bins + all weight transforms in one dispatch
    k_pre<<<321 + 72, 256, 0, stream>>>((int4*)cntp, 4 * N, W1, W1t, W2, b2,
                                        lin_W, lin_b, w2l, atom_table, at16);
    k_edge_w<<<egrid, 256, 0, stream>>>(edge_attr, bond_table, col, ew, rank, cntp, E);
    k_scan1<<<nb, SCAN_B, 0, stream>>>(cntp, off, bsums, N);
    k_scan2<<<1, 512, 0, stream>>>(bsums, nb);
    k_scan3<<<nb, SCAN_B, 0, stream>>>(off, bsums, N, E);
    k_fill<<<egrid, 256, 0, stream>>>(row, col, rank, off, ew, csr, E);

    // node pass: degree -> dinv -> scaled fp8 features
    k_node<<<(N + 7) / 8, 256, 0, stream>>>(x, at16, off, csr, dinv, h8, N);

    // pipeline
    k_gather1<<<(N + 7) / 8, 256, 0, stream>>>(h8, off, csr, dinv, hB, N);
    k_mm1<<<(N + 127) / 128, 256, 0, stream>>>(hB, W1t, b1, w2l, dinv, tbuf, N);
    k_gather2s<<<ngrid, 256, 0, stream>>>(tbuf, off, csr, dinv, w2l, out, N);
}